// Round 9
// baseline (21628.355 us; speedup 1.0000x reference)
//
#include <hip/hip_runtime.h>
#include <hip/hip_bf16.h>

// TrueMarkovChain v9: 64-WG recurrence (8 groups x 8 WGs, wide n-slices)
// + 192 concurrent xc-WGs in ONE persistent kernel. All cross-WG data sc0sc1
// (v6-proven memory model; no XCD assumptions). Counted-vmcnt weight rings,
// act burst overlapped with ring preload, guarded polls with dead-latch.

typedef __bf16 v8bf __attribute__((ext_vector_type(8)));
typedef float f32x4 __attribute__((ext_vector_type(4)));
typedef unsigned u32x4 __attribute__((ext_vector_type(4)));

__device__ inline f32x4 mfma16(v8bf a, v8bf b, f32x4 c) {
  return __builtin_amdgcn_mfma_f32_16x16x32_bf16(a, b, c, 0, 0, 0);
}
__device__ inline float silu_f(float x) { return x / (1.f + __expf(-x)); }
__device__ inline v8bf as8(f32x4 x) { union { f32x4 f; v8bf b; } u; u.f = x; return u.b; }
__device__ inline v8bf cvt8(float4 a, float4 b) {
  v8bf v;
  v[0] = (__bf16)a.x; v[1] = (__bf16)a.y; v[2] = (__bf16)a.z; v[3] = (__bf16)a.w;
  v[4] = (__bf16)b.x; v[5] = (__bf16)b.y; v[6] = (__bf16)b.z; v[7] = (__bf16)b.w;
  return v;
}
__device__ inline unsigned bfb(float v) {
  __bf16 b = (__bf16)v; unsigned short u; __builtin_memcpy(&u, &b, 2); return (unsigned)u;
}
__device__ inline void st16c(__bf16* p, float v) {
  unsigned u = bfb(v);
  asm volatile("global_store_short %0, %1, off sc0 sc1" :: "v"(p), "v"(u) : "memory");
}

template <int N> __device__ inline void vwait() {
  asm volatile("s_waitcnt vmcnt(%0)" :: "n"(N) : "memory");
  __builtin_amdgcn_sched_barrier(0);
}
__device__ inline void vwait_n(int n) {
  switch (n) {
    case 0: vwait<0>(); break;   case 2: vwait<2>(); break;
    case 4: vwait<4>(); break;   case 6: vwait<6>(); break;
    case 8: vwait<8>(); break;   case 10: vwait<10>(); break;
    case 12: vwait<12>(); break; case 14: vwait<14>(); break;
    case 16: vwait<16>(); break; case 20: vwait<20>(); break;
    default: vwait<24>(); break;
  }
}

// ---------------- guarded polls (sc0sc1), dead-latch --------------------------
__device__ inline void poll8(const unsigned* f, unsigned tgt, int* dead) {
  if (threadIdx.x < 2 && !*dead) {
    const unsigned* p = f + threadIdx.x * 4;
    int guard = 0;
    while (true) {
      u32x4 v;
      asm volatile("global_load_dwordx4 %0, %1, off sc0 sc1\n\ts_waitcnt vmcnt(0)"
                   : "=v"(v) : "v"(p) : "memory");
      if (v[0] >= tgt && v[1] >= tgt && v[2] >= tgt && v[3] >= tgt) break;
      if (++guard > (1 << 17)) { *dead = 1; break; }
      __builtin_amdgcn_s_sleep(2);
    }
  }
  __syncthreads();
}
__device__ inline void pollA(const unsigned* fC, const unsigned* fXt, unsigned t, int* dead) {
  if (threadIdx.x < 3 && !*dead) {
    int guard = 0;
    if (threadIdx.x < 2) {
      const unsigned* p = fC + threadIdx.x * 4;
      while (true) {
        u32x4 v;
        asm volatile("global_load_dwordx4 %0, %1, off sc0 sc1\n\ts_waitcnt vmcnt(0)"
                     : "=v"(v) : "v"(p) : "memory");
        if (v[0] >= t && v[1] >= t && v[2] >= t && v[3] >= t) break;
        if (++guard > (1 << 17)) { *dead = 1; break; }
        __builtin_amdgcn_s_sleep(2);
      }
    } else {
      while (true) {
        unsigned v;
        asm volatile("global_load_dword %0, %1, off sc0 sc1\n\ts_waitcnt vmcnt(0)"
                     : "=v"(v) : "v"(fXt) : "memory");
        if (v >= 1u) break;
        if (++guard > (1 << 17)) { *dead = 1; break; }
        __builtin_amdgcn_s_sleep(2);
      }
    }
  }
  __syncthreads();
}
__device__ inline void release(unsigned* fp, unsigned v) {
  asm volatile("s_waitcnt vmcnt(0)" ::: "memory");
  __syncthreads();
  if (threadIdx.x == 0)
    asm volatile("global_store_dword %0, %1, off sc0 sc1" :: "v"(fp), "v"(v) : "memory");
}

// ---------------- fp32 -> bf16 strided converter -----------------------------
__global__ void cvt_kernel(const float* __restrict__ src, __bf16* __restrict__ dst,
                           int total8, int log2cols, int sstride, int soff) {
  int i = blockIdx.x * 256 + threadIdx.x;
  if (i >= total8) return;
  long long e = (long long)i * 8;
  int r = (int)(e >> log2cols);
  int c = (int)(e & ((1LL << log2cols) - 1));
  const float* s = src + (size_t)r * sstride + soff + c;
  float4 f0 = *(const float4*)(s);
  float4 f1 = *(const float4*)(s + 4);
  *(v8bf*)(dst + e) = cvt8(f0, f1);
}

// ---- act staging: sc0sc1 burst -> swizzled LDS ------------------------------
template <int K>
__device__ inline void stage_issue(f32x4* v, const __bf16* src, int tid) {
  constexpr int KC = K / 8;
#pragma unroll
  for (int i = 0; i < K / 128; ++i) {
    int idx = tid + i * 256;
    int row = idx / KC, kc = idx % KC;
    asm volatile("global_load_dwordx4 %0, %1, off sc0 sc1"
                 : "=v"(v[i]) : "v"(src + (size_t)row * K + kc * 8));
  }
}
template <int K>
__device__ inline void stage_commit(char* lds, f32x4* v, int tid) {
  constexpr int KC = K / 8;
#pragma unroll
  for (int i = 0; i < K / 128; ++i) {
    int idx = tid + i * 256;
    int row = idx / KC, kc = idx % KC;
    unsigned byte = ((unsigned)(row * K + kc * 8) * 2) ^ ((unsigned)(row & 7) << 4);
    *(f32x4*)(lds + byte) = v[i];
  }
  __syncthreads();
}

// ---- weight ring: preload + run (acts from swizzled LDS) --------------------
template <int PFD, int NF, int KS>
__device__ inline void ring_pre(const __bf16* wtb, f32x4 (&rw)[PFD][NF]) {
#pragma unroll
  for (int j = 0; j < PFD; ++j)
#pragma unroll
    for (int f = 0; f < NF; ++f)
      asm volatile("global_load_dwordx4 %0, %1, off offset:%2"
                   : "=v"(rw[j][f]) : "v"(wtb + (size_t)f * 16 * KS), "n"(j * 64));
}
template <int KIT, int PFD, int NF, int KS>
__device__ inline void ring_run(const char* ldsa, int k0, const __bf16* wtb,
                                f32x4 (&rw)[PFD][NF], f32x4 (&acc)[NF], int lane) {
  const int lr = lane & 15, lc = lane >> 4;
#pragma unroll
  for (int it = 0; it < KIT; ++it) {
    vwait_n(((KIT - 1 - it) < (PFD - 1) ? (KIT - 1 - it) : (PFD - 1)) * NF);
    int k = k0 + it * 32 + lc * 8;
    unsigned byte = ((unsigned)(lr * KS + k) * 2) ^ ((unsigned)(lr & 7) << 4);
    v8bf a = *(const v8bf*)(ldsa + byte);
#pragma unroll
    for (int f = 0; f < NF; ++f) {
      v8bf b = as8(rw[it % PFD][f]);
      acc[f] = mfma16(a, b, acc[f]);
      if (it + PFD < KIT)
        asm volatile("global_load_dwordx4 %0, %1, off offset:%2"
                     : "=v"(rw[it % PFD][f])
                     : "v"(wtb + (size_t)f * 16 * KS), "n"((it + PFD) * 64));
    }
  }
}

// ---------------- fused persistent kernel ------------------------------------
// bid 0..63: recurrence (g = bid>>3, s = bid&7). bid 64..255: xc producer.
__global__ __launch_bounds__(256, 1) void fused_kernel(
    const __bf16* __restrict__ wWi1, const __bf16* __restrict__ wWi2,
    const __bf16* __restrict__ wWt1s, const __bf16* __restrict__ wWt2,
    const __bf16* __restrict__ wWt3, const __bf16* __restrict__ wWt1x,
    const __bf16* __restrict__ x0bf, const float* __restrict__ past,
    __bf16* __restrict__ sbf, __bf16* __restrict__ z1, __bf16* __restrict__ z2,
    const float* __restrict__ bi1, const float* __restrict__ bi2,
    const float* __restrict__ bt1, const float* __restrict__ bt2,
    const float* __restrict__ bt3,
    float* __restrict__ out, unsigned* __restrict__ flags) {
  __shared__ alignas(16) char actbuf[98304];  // 96KB: forces 1 WG/CU
  __shared__ int s_dead;
  const int bid = blockIdx.x;
  const int tid = threadIdx.x, wid = tid >> 6, lane = tid & 63;
  const int lr = lane & 15, lc = lane >> 4;
  const int cm = lc << 2, cn = lr;
  if (tid == 0) s_dead = 0;
  __syncthreads();
  unsigned* fX = flags + 1024;  // [4][512]

  if (bid >= 64) {
    // ================= X role: xc[t] = x_t @ Wt1x^T + bt1 ==================
    const int x = bid - 64;  // 0..191
    __bf16* xcw = (__bf16*)out;
    for (int j = x; j < 2044; j += 192) {
      const int t = 1 + (j >> 2), q = j & 3;
      const float* a0p = past + ((size_t)(wid * 32 + lr) * 512 + t) * 1024 + lc * 8;
      const float* a1p = a0p + (size_t)16 * 512 * 1024;
      for (int ch = 0; ch < 4; ++ch) {
        const int n0 = q * 512 + ch * 128;
        const __bf16* bp = wWt1x + (size_t)(n0 + lr) * 1024 + lc * 8;
        float btv[8];
#pragma unroll
        for (int f = 0; f < 8; ++f) btv[f] = bt1[n0 + f * 16 + cn];
        f32x4 acc[2][8] = {};
#pragma unroll 4
        for (int it = 0; it < 32; ++it) {
          float4 x00 = *(const float4*)(a0p + it * 32);
          float4 x01 = *(const float4*)(a0p + it * 32 + 4);
          float4 x10 = *(const float4*)(a1p + it * 32);
          float4 x11 = *(const float4*)(a1p + it * 32 + 4);
          v8bf av0 = cvt8(x00, x01), av1 = cvt8(x10, x11);
#pragma unroll
          for (int f = 0; f < 8; ++f) {
            v8bf b = *(const v8bf*)(bp + (size_t)f * 16 * 1024 + it * 32);
            acc[0][f] = mfma16(av0, b, acc[0][f]);
            acc[1][f] = mfma16(av1, b, acc[1][f]);
          }
        }
#pragma unroll
        for (int mf = 0; mf < 2; ++mf)
#pragma unroll
          for (int f = 0; f < 8; ++f)
#pragma unroll
            for (int r = 0; r < 4; ++r) {
              int m = wid * 32 + mf * 16 + cm + r, n = n0 + f * 16 + cn;
              st16c(xcw + ((size_t)m * 512 + t) * 2048 + n, acc[mf][f][r] + btv[f]);
            }
      }
      release(fX + (size_t)q * 512 + t, 1u);
    }
    return;
  }

  // ================= recurrence role =================
  const int g = bid >> 3, s = bid & 7;
  const int b0 = g * 16;
  unsigned* fA = flags + g * 64;
  unsigned* fB = fA + 16;
  unsigned* fC = fA + 32;
  __bf16* sbf_g = sbf + (size_t)g * 16 * 1024;
  __bf16* z1_g = z1 + (size_t)g * 16 * 2048;
  __bf16* z2_g = z2 + (size_t)g * 16 * 1024;
  const __bf16* xc = (const __bf16*)out;

  const int nAw = s * 256 + wid * 64;   // A: 4 frags of 16
  const int nBC = s * 128 + wid * 32;   // B/C/init: 2 frags of 16
  const __bf16* wtbA = wWt1s + (size_t)(nAw + lr) * 1024 + lc * 8;
  const __bf16* wtbB = wWt2 + (size_t)(nBC + lr) * 2048 + lc * 8;
  const __bf16* wtbC = wWt3 + (size_t)(nBC + lr) * 1024 + lc * 8;
  const __bf16* wtbI1 = wWi1 + (size_t)(nBC + lr) * 1024 + lc * 8;
  const __bf16* wtbI2 = wWi2 + (size_t)(nBC + lr) * 1024 + lc * 8;
  float bB[2], bC[2], bI1[2], bI2[2];
#pragma unroll
  for (int f = 0; f < 2; ++f) {
    bB[f] = bt2[nBC + f * 16 + cn];
    bC[f] = bt3[nBC + f * 16 + cn];
    bI1[f] = bi1[nBC + f * 16 + cn];
    bI2[f] = bi2[nBC + f * 16 + cn];
  }

  // ---- init-B: h0 = silu(x0 @ Wi1^T + bi1) -> z2 ----
  {
    f32x4 sv[8];
    stage_issue<1024>(sv, x0bf + (size_t)b0 * 1024, tid);
    f32x4 rw[8][2];
    ring_pre<8, 2, 1024>(wtbI1, rw);
    vwait<16>();
    stage_commit<1024>(actbuf, sv, tid);
    f32x4 acc[2] = {};
    ring_run<32, 8, 2, 1024>(actbuf, 0, wtbI1, rw, acc, lane);
#pragma unroll
    for (int f = 0; f < 2; ++f)
#pragma unroll
      for (int r = 0; r < 4; ++r)
        st16c(z2_g + (size_t)(cm + r) * 1024 + (nBC + f * 16 + cn),
              silu_f(acc[f][r] + bI1[f]));
    release(fB + s, 1u);
  }
  // ---- init-C: s0 = h0 @ Wi2^T + bi2 -> out[:,0,:], sbf ----
  {
    poll8(fB, 1u, &s_dead);
    f32x4 sv[8];
    stage_issue<1024>(sv, z2_g, tid);
    f32x4 rw[8][2];
    ring_pre<8, 2, 1024>(wtbI2, rw);
    vwait<16>();
    stage_commit<1024>(actbuf, sv, tid);
    f32x4 acc[2] = {};
    ring_run<32, 8, 2, 1024>(actbuf, 0, wtbI2, rw, acc, lane);
#pragma unroll
    for (int f = 0; f < 2; ++f)
#pragma unroll
      for (int r = 0; r < 4; ++r) {
        float v = acc[f][r] + bI2[f];
        out[(size_t)(b0 + cm + r) * 524288 + (nBC + f * 16 + cn)] = v;
        st16c(sbf_g + (size_t)(cm + r) * 1024 + (nBC + f * 16 + cn), v);
      }
    release(fC + s, 1u);
  }

  for (int t = 1; t < 512; ++t) {
    // ---- A: z1 = silu(s_prev @ Wt1s^T + xc[t]) ----
    {
      pollA(fC, fX + (size_t)(s >> 1) * 512 + t, (unsigned)t, &s_dead);
      f32x4 sv[8];
      stage_issue<1024>(sv, sbf_g, tid);
      unsigned xcu[4][4];
#pragma unroll
      for (int f = 0; f < 4; ++f)
#pragma unroll
        for (int r = 0; r < 4; ++r) {
          const __bf16* p = xc + ((size_t)(b0 + cm + r) * 512 + t) * 2048 +
                            (nAw + f * 16 + cn);
          asm volatile("global_load_ushort %0, %1, off sc0 sc1"
                       : "=v"(xcu[f][r]) : "v"(p));
        }
      f32x4 rw[6][4];
      ring_pre<6, 4, 1024>(wtbA, rw);
      vwait<24>();  // acts + xc retired; ring (24) in flight
      stage_commit<1024>(actbuf, sv, tid);
      f32x4 acc[4] = {};
      ring_run<32, 6, 4, 1024>(actbuf, 0, wtbA, rw, acc, lane);
#pragma unroll
      for (int f = 0; f < 4; ++f)
#pragma unroll
        for (int r = 0; r < 4; ++r) {
          float xv = __uint_as_float(xcu[f][r] << 16);
          st16c(z1_g + (size_t)(cm + r) * 2048 + (nAw + f * 16 + cn),
                silu_f(acc[f][r] + xv));
        }
      release(fA + s, (unsigned)t);
    }
    // ---- B: z2 = silu(z1 @ Wt2^T + bt2) ----
    {
      poll8(fA, (unsigned)t, &s_dead);
      f32x4 sv[16];
      stage_issue<2048>(sv, z1_g, tid);
      f32x4 rw[8][2];
      ring_pre<8, 2, 2048>(wtbB, rw);
      vwait<16>();
      stage_commit<2048>(actbuf, sv, tid);
      f32x4 acc[2] = {};
      ring_run<64, 8, 2, 2048>(actbuf, 0, wtbB, rw, acc, lane);
#pragma unroll
      for (int f = 0; f < 2; ++f)
#pragma unroll
        for (int r = 0; r < 4; ++r)
          st16c(z2_g + (size_t)(cm + r) * 1024 + (nBC + f * 16 + cn),
                silu_f(acc[f][r] + bB[f]));
      release(fB + s, (unsigned)(t + 1));
    }
    // ---- C: s = z2 @ Wt3^T + bt3 -> out[:,t,:], sbf ----
    {
      poll8(fB, (unsigned)(t + 1), &s_dead);
      f32x4 sv[8];
      stage_issue<1024>(sv, z2_g, tid);
      f32x4 rw[8][2];
      ring_pre<8, 2, 1024>(wtbC, rw);
      vwait<16>();
      stage_commit<1024>(actbuf, sv, tid);
      f32x4 acc[2] = {};
      ring_run<32, 8, 2, 1024>(actbuf, 0, wtbC, rw, acc, lane);
#pragma unroll
      for (int f = 0; f < 2; ++f)
#pragma unroll
        for (int r = 0; r < 4; ++r) {
          float v = acc[f][r] + bC[f];
          out[(size_t)(b0 + cm + r) * 524288 + (size_t)t * 1024 + (nBC + f * 16 + cn)] = v;
          st16c(sbf_g + (size_t)(cm + r) * 1024 + (nBC + f * 16 + cn), v);
        }
      release(fC + s, (unsigned)(t + 1));
    }
  }
}

// ---------------- host launcher ----------------------------------------------
extern "C" void kernel_launch(void* const* d_in, const int* in_sizes, int n_in,
                              void* d_out, int out_size, void* d_ws, size_t ws_size,
                              hipStream_t stream) {
  (void)in_sizes; (void)n_in; (void)out_size; (void)ws_size;
  const float* past = (const float*)d_in[0];
  const float* Wi1 = (const float*)d_in[1];
  const float* bi1 = (const float*)d_in[2];
  const float* Wi2 = (const float*)d_in[3];
  const float* bi2 = (const float*)d_in[4];
  const float* Wt1 = (const float*)d_in[5];
  const float* bt1 = (const float*)d_in[6];
  const float* Wt2 = (const float*)d_in[7];
  const float* bt2 = (const float*)d_in[8];
  const float* Wt3 = (const float*)d_in[9];
  const float* bt3 = (const float*)d_in[10];
  float* out = (float*)d_out;

  char* ws = (char*)d_ws;
  size_t off = 0;
  unsigned* flags = (unsigned*)(ws + off); off += 16384;
  __bf16* wWi1 = (__bf16*)(ws + off);  off += (size_t)1024 * 1024 * 2;
  __bf16* wWi2 = (__bf16*)(ws + off);  off += (size_t)1024 * 1024 * 2;
  __bf16* wWt1s = (__bf16*)(ws + off); off += (size_t)2048 * 1024 * 2;
  __bf16* wWt1x = (__bf16*)(ws + off); off += (size_t)2048 * 1024 * 2;
  __bf16* wWt2 = (__bf16*)(ws + off);  off += (size_t)1024 * 2048 * 2;
  __bf16* wWt3 = (__bf16*)(ws + off);  off += (size_t)1024 * 1024 * 2;
  __bf16* x0bf = (__bf16*)(ws + off);  off += (size_t)128 * 1024 * 2;
  __bf16* sbf = (__bf16*)(ws + off);   off += (size_t)128 * 1024 * 2;
  __bf16* z1 = (__bf16*)(ws + off);    off += (size_t)128 * 2048 * 2;
  __bf16* z2 = (__bf16*)(ws + off);    off += (size_t)128 * 1024 * 2;

  hipMemsetAsync(flags, 0, 16384, stream);

  auto cvt = [&](const float* s, __bf16* d, int rows, int cols, int log2c,
                 int sstride, int soff) {
    int total8 = rows * cols / 8;
    cvt_kernel<<<dim3((total8 + 255) / 256), dim3(256), 0, stream>>>(
        s, d, total8, log2c, sstride, soff);
  };
  cvt(Wi1, wWi1, 1024, 1024, 10, 1024, 0);
  cvt(Wi2, wWi2, 1024, 1024, 10, 1024, 0);
  cvt(Wt1, wWt1s, 2048, 1024, 10, 2048, 0);
  cvt(Wt1, wWt1x, 2048, 1024, 10, 2048, 1024);
  cvt(Wt2, wWt2, 1024, 2048, 11, 2048, 0);
  cvt(Wt3, wWt3, 1024, 1024, 10, 1024, 0);
  cvt(past, x0bf, 128, 1024, 10, 512 * 1024, 0);

  fused_kernel<<<dim3(256), dim3(256), 0, stream>>>(
      wWi1, wWi2, wWt1s, wWt2, wWt3, wWt1x, x0bf, past,
      sbf, z1, z2, bi1, bi2, bt1, bt2, bt3, out, flags);
}

// Round 11
// 9457.850 us; speedup vs baseline: 2.2868x; 2.2868x over previous
//
#include <hip/hip_runtime.h>
#include <hip/hip_bf16.h>

// TrueMarkovChain v11: v10 with the init-B vmcnt ordering bug fixed
// (acts staged before ring preload; vwait<0> retires acts before LDS commit).
// Structure: v6 (8 groups x 32 WGs), sc0sc1 exchange, coalesced transposed
// act stores, 4x act replicas, ring-preload-before-poll, Wt3 LDS-pinned,
// v7 xc prologue. Guarded polls + dead-latch.

typedef __bf16 v8bf __attribute__((ext_vector_type(8)));
typedef float f32x4 __attribute__((ext_vector_type(4)));
typedef unsigned u32x4 __attribute__((ext_vector_type(4)));

#define REP1 (128 * 2048)
#define REP2 (128 * 1024)

__device__ inline f32x4 mfma16(v8bf a, v8bf b, f32x4 c) {
  return __builtin_amdgcn_mfma_f32_16x16x32_bf16(a, b, c, 0, 0, 0);
}
__device__ inline float silu_f(float x) { return x / (1.f + __expf(-x)); }
__device__ inline v8bf as8(f32x4 x) { union { f32x4 f; v8bf b; } u; u.f = x; return u.b; }
__device__ inline v8bf cvt8(float4 a, float4 b) {
  v8bf v;
  v[0] = (__bf16)a.x; v[1] = (__bf16)a.y; v[2] = (__bf16)a.z; v[3] = (__bf16)a.w;
  v[4] = (__bf16)b.x; v[5] = (__bf16)b.y; v[6] = (__bf16)b.z; v[7] = (__bf16)b.w;
  return v;
}
__device__ inline unsigned bfb(float v) {
  __bf16 b = (__bf16)v; unsigned short u; __builtin_memcpy(&u, &b, 2); return (unsigned)u;
}

#define CLOADP(dst, base, boff)                                        \
  asm volatile("global_load_dwordx4 %0, %1, off offset:%2"             \
               : "=v"(dst) : "v"(base), "n"(boff))
#define CLOADC(dst, base)                                              \
  asm volatile("global_load_dwordx4 %0, %1, off sc0 sc1" : "=v"(dst) : "v"(base))

template <int N> __device__ inline void vwait() {
  asm volatile("s_waitcnt vmcnt(%0)" :: "n"(N) : "memory");
  __builtin_amdgcn_sched_barrier(0);
}
__device__ inline void vwait_n(int n) {
  switch (n) {
    case 0: vwait<0>(); break;   case 1: vwait<1>(); break;
    case 2: vwait<2>(); break;   case 3: vwait<3>(); break;
    case 4: vwait<4>(); break;   case 5: vwait<5>(); break;
    case 6: vwait<6>(); break;   case 7: vwait<7>(); break;
    case 8: vwait<8>(); break;   case 9: vwait<9>(); break;
    case 10: vwait<10>(); break; case 11: vwait<11>(); break;
    case 12: vwait<12>(); break; case 13: vwait<13>(); break;
    case 14: vwait<14>(); break; default: vwait<15>(); break;
  }
}

__device__ inline void poll32(const unsigned* f, unsigned tgt, int* dead) {
  if (threadIdx.x < 8 && !*dead) {
    const unsigned* p = f + threadIdx.x * 4;
    int guard = 0;
    while (true) {
      u32x4 v;
      asm volatile("global_load_dwordx4 %0, %1, off sc0 sc1\n\ts_waitcnt vmcnt(0)"
                   : "=v"(v) : "v"(p) : "memory");
      if (v[0] >= tgt && v[1] >= tgt && v[2] >= tgt && v[3] >= tgt) break;
      if (++guard > (1 << 18)) { *dead = 1; break; }
      __builtin_amdgcn_s_sleep(1);
    }
  }
  __syncthreads();
}
__device__ inline void release(unsigned* f, int slot, unsigned v) {
  asm volatile("s_waitcnt vmcnt(0)" ::: "memory");
  __syncthreads();
  if (threadIdx.x == 0)
    asm volatile("global_store_dword %0, %1, off sc0 sc1" :: "v"(f + slot), "v"(v) : "memory");
}

// ---------------- fp32 -> bf16 strided converter -----------------------------
__global__ void cvt_kernel(const float* __restrict__ src, __bf16* __restrict__ dst,
                           int total8, int log2cols, int sstride, int soff) {
  int i = blockIdx.x * 256 + threadIdx.x;
  if (i >= total8) return;
  long long e = (long long)i * 8;
  int r = (int)(e >> log2cols);
  int c = (int)(e & ((1LL << log2cols) - 1));
  const float* s = src + (size_t)r * sstride + soff + c;
  float4 f0 = *(const float4*)(s);
  float4 f1 = *(const float4*)(s + 4);
  *(v8bf*)(dst + e) = cvt8(f0, f1);
}

// ---------------- xc[b][t] = x_t @ Wt1x^T + bt1 (v7-proven) ------------------
__global__ __launch_bounds__(512, 1) void xc_gemm_kernel(
    const float* __restrict__ past, const __bf16* __restrict__ w1x,
    const float* __restrict__ bt1, __bf16* __restrict__ xc) {
  const int t = blockIdx.z + 1;
  const int mh = blockIdx.y;
  const int nb = blockIdx.x;
  const int tid = threadIdx.x, wid = tid >> 6, lane = tid & 63;
  const int wm = wid >> 2, wn = wid & 3;
  const int m0 = mh * 64 + wm * 32;
  const int n0 = nb * 512 + wn * 128;
  const int lr = lane & 15, lc = lane >> 4;
  f32x4 acc[2][8] = {};
  const float* a0p = past + ((size_t)(m0 + lr) * 512 + t) * 1024 + lc * 8;
  const float* a1p = a0p + (size_t)16 * 512 * 1024;
  const __bf16* bp = w1x + (size_t)(n0 + lr) * 1024 + lc * 8;
#pragma unroll 4
  for (int k = 0; k < 1024; k += 32) {
    float4 x00 = *(const float4*)(a0p + k);
    float4 x01 = *(const float4*)(a0p + k + 4);
    float4 x10 = *(const float4*)(a1p + k);
    float4 x11 = *(const float4*)(a1p + k + 4);
    v8bf a0 = cvt8(x00, x01), a1 = cvt8(x10, x11);
#pragma unroll
    for (int j = 0; j < 8; ++j) {
      v8bf b = *(const v8bf*)(bp + (size_t)j * 16 * 1024 + k);
      acc[0][j] = mfma16(a0, b, acc[0][j]);
      acc[1][j] = mfma16(a1, b, acc[1][j]);
    }
  }
  const int cm = lc << 2, cn = lr;
#pragma unroll
  for (int f = 0; f < 2; ++f)
#pragma unroll
    for (int j = 0; j < 8; ++j) {
      int n = n0 + j * 16 + cn;
      float bias = bt1[n];
#pragma unroll
      for (int r = 0; r < 4; ++r) {
        int m = m0 + f * 16 + cm + r;
        xc[((size_t)m * 512 + t) * 2048 + n] = (__bf16)(acc[f][j][r] + bias);
      }
    }
}

// ---- act staging (sc0sc1) -> swizzled LDS -----------------------------------
template <int K>
__device__ inline void stage_issue(f32x4* v, const __bf16* src, int tid) {
  constexpr int KC = K / 8;
#pragma unroll
  for (int i = 0; i < K / 128; ++i) {
    int idx = tid + i * 256;
    int row = idx / KC, kc = idx % KC;
    CLOADC(v[i], src + (size_t)row * K + kc * 8);
  }
}
template <int K>
__device__ inline void stage_commit(char* lds, f32x4* v, int tid) {
  constexpr int KC = K / 8;
#pragma unroll
  for (int i = 0; i < K / 128; ++i) {
    int idx = tid + i * 256;
    int row = idx / KC, kc = idx % KC;
    unsigned byte = ((unsigned)(row * K + kc * 8) * 2) ^ ((unsigned)(row & 7) << 4);
    *(f32x4*)(lds + byte) = v[i];
  }
  __syncthreads();
}

// ---- ring GEMM: swizzled LDS act + plain global weight ring (NF=1) ----------
template <int KIT, int PFD, int KSB>
__device__ inline f32x4 ring_run1(const char* ldsa, int k0, const __bf16* wtb,
                                  f32x4 (&rw)[PFD], int lane) {
  const int lr = lane & 15, lc = lane >> 4;
  f32x4 acc = {0.f, 0.f, 0.f, 0.f};
#pragma unroll
  for (int it = 0; it < KIT; ++it) {
    vwait_n((KIT - 1 - it) < (PFD - 1) ? (KIT - 1 - it) : (PFD - 1));
    v8bf b = as8(rw[it % PFD]);
    if (it + PFD < KIT) CLOADP(rw[it % PFD], wtb, (it + PFD) * 64);
    int k = k0 + it * 32 + lc * 8;
    unsigned byte = ((unsigned)(lr * KSB + k) * 2) ^ ((unsigned)(lr & 7) << 4);
    v8bf a = *(const v8bf*)(ldsa + byte);
    acc = mfma16(a, b, acc);
  }
  return acc;
}
template <int PFD>
__device__ inline void ring_pre(const __bf16* wtb, f32x4 (&rw)[PFD]) {
#pragma unroll
  for (int j = 0; j < PFD; ++j) CLOADP(rw[j], wtb, j * 64);
}

// ---- LDS act + LDS weights ([kb][32][8]) ------------------------------------
__device__ inline f32x4 gemm_aa16(const char* ldsa, int k0, const char* ldsw,
                                  int kb0, int col, int lane) {
  const int lr = lane & 15, lc = lane >> 4;
  f32x4 acc = {0.f, 0.f, 0.f, 0.f};
#pragma unroll
  for (int it = 0; it < 16; ++it) {
    int k = k0 + it * 32 + lc * 8;
    unsigned abyte = ((unsigned)(lr * 1024 + k) * 2) ^ ((unsigned)(lr & 7) << 4);
    v8bf a = *(const v8bf*)(ldsa + abyte);
    v8bf b = *(const v8bf*)(ldsw + (size_t)((kb0 + it * 4 + lc) * 32 + col) * 16);
    acc = mfma16(a, b, acc);
  }
  return acc;
}

// ---------------- persistent recurrence --------------------------------------
__global__ __launch_bounds__(256, 1) void recurrent_kernel(
    const __bf16* __restrict__ wWi1, const __bf16* __restrict__ wWi2,
    const __bf16* __restrict__ wWt1s, const __bf16* __restrict__ wWt2,
    const __bf16* __restrict__ wWt3, const __bf16* __restrict__ x0bf,
    __bf16* __restrict__ sbf, __bf16* __restrict__ z1, __bf16* __restrict__ z2,
    const float* __restrict__ bi1, const float* __restrict__ bi2,
    const float* __restrict__ bt2, const float* __restrict__ bt3,
    float* __restrict__ out, unsigned* __restrict__ flags) {
  __shared__ alignas(16) char actbuf[65536];   // [16][K<=2048] swizzled acts
  __shared__ alignas(16) char wt3buf[65536];   // Wt3 slice [kb=128][32][8]
  __shared__ alignas(16) char scratch[4096];   // tpose (A) / red+fin (B,C)
  __shared__ int s_dead;
  const int bid = blockIdx.x;
  const int g = bid >> 5, s = bid & 31;
  const int tid = threadIdx.x, wid = tid >> 6, lane = tid & 63;
  const int lr = lane & 15, lc = lane >> 4;
  const int cm = lc << 2, cn = lr;
  const int wn = wid & 1, wk = wid >> 1;
  const int b0 = g * 16;
  const int rp = s & 3;
  if (tid == 0) s_dead = 0;

  unsigned* fA = flags + g * 96;
  unsigned* fB = fA + 32;
  unsigned* fC = fA + 64;
  const __bf16* xc = (const __bf16*)out;
  __bf16* tposeb = (__bf16*)scratch;
  float* red = (float*)scratch;
  float* fin = (float*)(scratch + 2048);

  // stage full Wt3 slice (cols s*32..+32, K=1024) -> [kb=128][32][8]
  {
    const __bf16* wg = wWt3 + (size_t)s * 32 * 1024;
    for (int idx = tid; idx < 4096; idx += 256) {
      int kb = idx >> 5, c = idx & 31;
      *(f32x4*)(wt3buf + (size_t)idx * 16) = *(const f32x4*)(wg + (size_t)c * 1024 + kb * 8);
    }
  }

  const int nBC = s * 32 + wn * 16 + cn;
  const int nA = s * 64 + wid * 16 + cn;
  const float bB = bt2[nBC], bC = bt3[nBC];
  const float bI1 = bi1[nBC], bI2 = bi2[nBC];

  // coalesced store helper: fin [16][32] fp32 -> bf16 pairs, 4 replicas
  auto storeBC = [&](__bf16* base, int ldk, int colbase) {
    int row = tid >> 4, col = (tid * 2) & 31;
    unsigned d = bfb(fin[row * 32 + col]) | (bfb(fin[row * 32 + col + 1]) << 16);
#pragma unroll
    for (int rep = 0; rep < 4; ++rep) {
      __bf16* p = base + (size_t)rep * REP2 + (size_t)(b0 + row) * ldk + colbase + col;
      asm volatile("global_store_dword %0, %1, off sc0 sc1" :: "v"(p), "v"(d) : "memory");
    }
  };

  // ---- init-B: h0 = silu(x0 @ Wi1^T + bi1) -> z2 ----
  // FIX (v10 NaN): acts issued FIRST, then ring; vwait<0> retires everything
  // before the LDS commit (vmcnt retires oldest-first — v10's vwait<8> after
  // ring-first issue retired the ring, not the acts).
  {
    f32x4 sv[8];
    stage_issue<1024>(sv, x0bf + (size_t)b0 * 1024, tid);
    f32x4 rw[8];
    ring_pre<8>(wWi1 + (size_t)(nBC - cn + lr) * 1024 + wk * 512 + lc * 8, rw);
    vwait<0>();
    stage_commit<1024>(actbuf, sv, tid);
    f32x4 acc = ring_run1<16, 8, 1024>(actbuf, wk * 512,
        wWi1 + (size_t)(nBC - cn + lr) * 1024 + wk * 512 + lc * 8, rw, lane);
    if (wk) {
#pragma unroll
      for (int r = 0; r < 4; ++r) red[wn * 256 + (cm + r) * 16 + cn] = acc[r];
    }
    __syncthreads();
    if (!wk) {
#pragma unroll
      for (int r = 0; r < 4; ++r)
        fin[(cm + r) * 32 + wn * 16 + cn] =
            silu_f(acc[r] + red[wn * 256 + (cm + r) * 16 + cn] + bI1);
    }
    __syncthreads();
    storeBC(z2, 1024, s * 32);
    release(fB, s, 1u);
  }
  // ---- init-C: s0 = h0 @ Wi2^T + bi2 -> out[:,0,:], sbf ----
  {
    f32x4 rw[8];
    ring_pre<8>(wWi2 + (size_t)(nBC - cn + lr) * 1024 + wk * 512 + lc * 8, rw);
    poll32(fB, 1u, &s_dead);
    f32x4 sv[8];
    stage_issue<1024>(sv, z2 + (size_t)rp * REP2 + (size_t)b0 * 1024, tid);
    vwait<0>();
    stage_commit<1024>(actbuf, sv, tid);
    f32x4 acc = ring_run1<16, 8, 1024>(actbuf, wk * 512,
        wWi2 + (size_t)(nBC - cn + lr) * 1024 + wk * 512 + lc * 8, rw, lane);
    if (wk) {
#pragma unroll
      for (int r = 0; r < 4; ++r) red[wn * 256 + (cm + r) * 16 + cn] = acc[r];
    }
    __syncthreads();
    if (!wk) {
#pragma unroll
      for (int r = 0; r < 4; ++r)
        fin[(cm + r) * 32 + wn * 16 + cn] =
            acc[r] + red[wn * 256 + (cm + r) * 16 + cn] + bI2;
    }
    __syncthreads();
    {
      int row = tid >> 4, col = (tid * 2) & 31;
      float2 o; o.x = fin[row * 32 + col]; o.y = fin[row * 32 + col + 1];
      *(float2*)(out + (size_t)(b0 + row) * 524288 + s * 32 + col) = o;
    }
    storeBC(sbf, 1024, s * 32);
    release(fC, s, 1u);
  }

  for (int t = 1; t < 512; ++t) {
    // ---- A: z1 = silu(s_prev @ Wt1s^T + xc[t]) ----
    {
      const __bf16* wtbA = wWt1s + (size_t)(s * 64 + wid * 16 + lr) * 1024 + lc * 8;
      f32x4 rw[12];
      ring_pre<12>(wtbA, rw);
      poll32(fC, (unsigned)t, &s_dead);
      unsigned xcu[4];
#pragma unroll
      for (int r = 0; r < 4; ++r) {
        const __bf16* p = xc + ((size_t)(b0 + cm + r) * 512 + t) * 2048 + nA;
        asm volatile("global_load_ushort %0, %1, off sc0 sc1" : "=v"(xcu[r]) : "v"(p));
      }
      f32x4 sv[8];
      stage_issue<1024>(sv, sbf + (size_t)rp * REP2 + (size_t)b0 * 1024, tid);
      vwait<0>();
      stage_commit<1024>(actbuf, sv, tid);
      f32x4 acc = ring_run1<32, 12, 1024>(actbuf, 0, wtbA, rw, lane);
#pragma unroll
      for (int r = 0; r < 4; ++r) {
        float xv = __uint_as_float(xcu[r] << 16);
        tposeb[(cm + r) * 64 + wid * 16 + cn] = (__bf16)silu_f(acc[r] + xv);
      }
      __syncthreads();
      {
        int row = tid >> 4, col = (tid * 4) & 63;
        unsigned long long d = *(const unsigned long long*)(tposeb + row * 64 + col);
#pragma unroll
        for (int rep = 0; rep < 4; ++rep) {
          __bf16* p = z1 + (size_t)rep * REP1 + (size_t)(b0 + row) * 2048 + s * 64 + col;
          asm volatile("global_store_dwordx2 %0, %1, off sc0 sc1" :: "v"(p), "v"(d) : "memory");
        }
      }
      release(fA, s, (unsigned)t);
    }
    // ---- B: z2 = silu(z1 @ Wt2^T + bt2) ----
    {
      const __bf16* wtbB = wWt2 + (size_t)(nBC - cn + lr) * 2048 + wk * 1024 + lc * 8;
      f32x4 rw[12];
      ring_pre<12>(wtbB, rw);
      poll32(fA, (unsigned)t, &s_dead);
      f32x4 sv[16];
      stage_issue<2048>(sv, z1 + (size_t)rp * REP1 + (size_t)b0 * 2048, tid);
      vwait<0>();
      stage_commit<2048>(actbuf, sv, tid);
      f32x4 acc = ring_run1<32, 12, 2048>(actbuf, wk * 1024, wtbB, rw, lane);
      if (wk) {
#pragma unroll
        for (int r = 0; r < 4; ++r) red[wn * 256 + (cm + r) * 16 + cn] = acc[r];
      }
      __syncthreads();
      if (!wk) {
#pragma unroll
        for (int r = 0; r < 4; ++r)
          fin[(cm + r) * 32 + wn * 16 + cn] =
              silu_f(acc[r] + red[wn * 256 + (cm + r) * 16 + cn] + bB);
      }
      __syncthreads();
      storeBC(z2, 1024, s * 32);
      release(fB, s, (unsigned)(t + 1));
    }
    // ---- C: s = z2 @ Wt3^T + bt3 -> out[:,t,:], sbf (Wt3 in LDS) ----
    {
      poll32(fB, (unsigned)(t + 1), &s_dead);
      f32x4 sv[8];
      stage_issue<1024>(sv, z2 + (size_t)rp * REP2 + (size_t)b0 * 1024, tid);
      vwait<0>();
      stage_commit<1024>(actbuf, sv, tid);
      f32x4 acc = gemm_aa16(actbuf, wk * 512, wt3buf, wk * 64, wn * 16 + lr, lane);
      if (wk) {
#pragma unroll
        for (int r = 0; r < 4; ++r) red[wn * 256 + (cm + r) * 16 + cn] = acc[r];
      }
      __syncthreads();
      if (!wk) {
#pragma unroll
        for (int r = 0; r < 4; ++r)
          fin[(cm + r) * 32 + wn * 16 + cn] =
              acc[r] + red[wn * 256 + (cm + r) * 16 + cn] + bC;
      }
      __syncthreads();
      {
        int row = tid >> 4, col = (tid * 2) & 31;
        float2 o; o.x = fin[row * 32 + col]; o.y = fin[row * 32 + col + 1];
        *(float2*)(out + (size_t)(b0 + row) * 524288 + (size_t)t * 1024 + s * 32 + col) = o;
      }
      storeBC(sbf, 1024, s * 32);
      release(fC, s, (unsigned)(t + 1));
    }
  }
}

// ---------------- host launcher ----------------------------------------------
extern "C" void kernel_launch(void* const* d_in, const int* in_sizes, int n_in,
                              void* d_out, int out_size, void* d_ws, size_t ws_size,
                              hipStream_t stream) {
  (void)in_sizes; (void)n_in; (void)out_size; (void)ws_size;
  const float* past = (const float*)d_in[0];
  const float* Wi1 = (const float*)d_in[1];
  const float* bi1 = (const float*)d_in[2];
  const float* Wi2 = (const float*)d_in[3];
  const float* bi2 = (const float*)d_in[4];
  const float* Wt1 = (const float*)d_in[5];
  const float* bt1 = (const float*)d_in[6];
  const float* Wt2 = (const float*)d_in[7];
  const float* bt2 = (const float*)d_in[8];
  const float* Wt3 = (const float*)d_in[9];
  const float* bt3 = (const float*)d_in[10];
  float* out = (float*)d_out;

  char* ws = (char*)d_ws;
  size_t off = 0;
  unsigned* flags = (unsigned*)(ws + off); off += 4096;
  __bf16* wWi1 = (__bf16*)(ws + off);  off += (size_t)1024 * 1024 * 2;
  __bf16* wWi2 = (__bf16*)(ws + off);  off += (size_t)1024 * 1024 * 2;
  __bf16* wWt1s = (__bf16*)(ws + off); off += (size_t)2048 * 1024 * 2;
  __bf16* wWt1x = (__bf16*)(ws + off); off += (size_t)2048 * 1024 * 2;
  __bf16* wWt2 = (__bf16*)(ws + off);  off += (size_t)1024 * 2048 * 2;
  __bf16* wWt3 = (__bf16*)(ws + off);  off += (size_t)1024 * 1024 * 2;
  __bf16* x0bf = (__bf16*)(ws + off);  off += (size_t)128 * 1024 * 2;
  __bf16* sbf = (__bf16*)(ws + off);   off += (size_t)4 * REP2 * 2;
  __bf16* z1 = (__bf16*)(ws + off);    off += (size_t)4 * REP1 * 2;
  __bf16* z2 = (__bf16*)(ws + off);    off += (size_t)4 * REP2 * 2;

  hipMemsetAsync(flags, 0, 4096, stream);

  auto cvt = [&](const float* s, __bf16* d, int rows, int cols, int log2c,
                 int sstride, int soff) {
    int total8 = rows * cols / 8;
    cvt_kernel<<<dim3((total8 + 255) / 256), dim3(256), 0, stream>>>(
        s, d, total8, log2c, sstride, soff);
  };
  cvt(Wi1, wWi1, 1024, 1024, 10, 1024, 0);
  cvt(Wi2, wWi2, 1024, 1024, 10, 1024, 0);
  cvt(Wt1, wWt1s, 2048, 1024, 10, 2048, 0);
  cvt(Wt1, wWt1x, 2048, 1024, 10, 2048, 1024);
  cvt(Wt2, wWt2, 1024, 2048, 11, 2048, 0);
  cvt(Wt3, wWt3, 1024, 1024, 10, 1024, 0);
  cvt(past, x0bf, 128, 1024, 10, 512 * 1024, 0);

  xc_gemm_kernel<<<dim3(4, 2, 511), dim3(512), 0, stream>>>(
      past, wWt1x, bt1, (__bf16*)d_out);

  recurrent_kernel<<<dim3(256), dim3(256), 0, stream>>>(
      wWi1, wWi2, wWt1s, wWt2, wWt3, x0bf, sbf, z1, z2,
      bi1, bi2, bt2, bt3, out, flags);
}

// Round 12
// 8106.459 us; speedup vs baseline: 2.6680x; 1.1667x over previous
//
#include <hip/hip_runtime.h>
#include <hip/hip_bf16.h>

// TrueMarkovChain v12: hop elimination via weight composition.
//   z1_t = silu(W13·z2_{t-1} + b13 + xc_t),  W13 = Wt1s@Wt3 (W1i2 for t=1)
// Serial chain = A->B (2 hops/step). C (out = Wt3·z2+bt3) runs off-path after
// fA release, reusing the staged z2 tile (hidden in straggler wait). z2
// double-buffered; sbf deleted. Exchange: sc0sc1 + coalesced stores + 4x
// replicas (v11-proven). Guarded polls + dead-latch.

typedef __bf16 v8bf __attribute__((ext_vector_type(8)));
typedef float f32x4 __attribute__((ext_vector_type(4)));
typedef unsigned u32x4 __attribute__((ext_vector_type(4)));

#define REP1 (128 * 2048)
#define REP2 (128 * 1024)

__device__ inline f32x4 mfma16(v8bf a, v8bf b, f32x4 c) {
  return __builtin_amdgcn_mfma_f32_16x16x32_bf16(a, b, c, 0, 0, 0);
}
__device__ inline float silu_f(float x) { return x / (1.f + __expf(-x)); }
__device__ inline v8bf as8(f32x4 x) { union { f32x4 f; v8bf b; } u; u.f = x; return u.b; }
__device__ inline v8bf cvt8(float4 a, float4 b) {
  v8bf v;
  v[0] = (__bf16)a.x; v[1] = (__bf16)a.y; v[2] = (__bf16)a.z; v[3] = (__bf16)a.w;
  v[4] = (__bf16)b.x; v[5] = (__bf16)b.y; v[6] = (__bf16)b.z; v[7] = (__bf16)b.w;
  return v;
}
__device__ inline unsigned bfb(float v) {
  __bf16 b = (__bf16)v; unsigned short u; __builtin_memcpy(&u, &b, 2); return (unsigned)u;
}

#define CLOADP(dst, base, boff)                                        \
  asm volatile("global_load_dwordx4 %0, %1, off offset:%2"             \
               : "=v"(dst) : "v"(base), "n"(boff))
#define CLOADC(dst, base)                                              \
  asm volatile("global_load_dwordx4 %0, %1, off sc0 sc1" : "=v"(dst) : "v"(base))

template <int N> __device__ inline void vwait() {
  asm volatile("s_waitcnt vmcnt(%0)" :: "n"(N) : "memory");
  __builtin_amdgcn_sched_barrier(0);
}
__device__ inline void vwait_n(int n) {
  switch (n) {
    case 0: vwait<0>(); break;   case 1: vwait<1>(); break;
    case 2: vwait<2>(); break;   case 3: vwait<3>(); break;
    case 4: vwait<4>(); break;   case 5: vwait<5>(); break;
    case 6: vwait<6>(); break;   case 7: vwait<7>(); break;
    case 8: vwait<8>(); break;   case 9: vwait<9>(); break;
    case 10: vwait<10>(); break; case 11: vwait<11>(); break;
    case 12: vwait<12>(); break; case 13: vwait<13>(); break;
    case 14: vwait<14>(); break; default: vwait<15>(); break;
  }
}

__device__ inline void poll32(const unsigned* f, unsigned tgt, int* dead) {
  if (threadIdx.x < 8 && !*dead) {
    const unsigned* p = f + threadIdx.x * 4;
    int guard = 0;
    while (true) {
      u32x4 v;
      asm volatile("global_load_dwordx4 %0, %1, off sc0 sc1\n\ts_waitcnt vmcnt(0)"
                   : "=v"(v) : "v"(p) : "memory");
      if (v[0] >= tgt && v[1] >= tgt && v[2] >= tgt && v[3] >= tgt) break;
      if (++guard > (1 << 18)) { *dead = 1; break; }
      __builtin_amdgcn_s_sleep(1);
    }
  }
  __syncthreads();
}
__device__ inline void release(unsigned* f, int slot, unsigned v) {
  asm volatile("s_waitcnt vmcnt(0)" ::: "memory");
  __syncthreads();
  if (threadIdx.x == 0)
    asm volatile("global_store_dword %0, %1, off sc0 sc1" :: "v"(f + slot), "v"(v) : "memory");
}

// ---------------- fp32 -> bf16 strided converter -----------------------------
__global__ void cvt_kernel(const float* __restrict__ src, __bf16* __restrict__ dst,
                           int total8, int log2cols, int sstride, int soff) {
  int i = blockIdx.x * 256 + threadIdx.x;
  if (i >= total8) return;
  long long e = (long long)i * 8;
  int r = (int)(e >> log2cols);
  int c = (int)(e & ((1LL << log2cols) - 1));
  const float* s = src + (size_t)r * sstride + soff + c;
  float4 f0 = *(const float4*)(s);
  float4 f1 = *(const float4*)(s + 4);
  *(v8bf*)(dst + e) = cvt8(f0, f1);
}

// ---------------- fp32 (R x C) -> bf16 transposed (C x R) --------------------
__global__ void tpose_kernel(const float* __restrict__ src, __bf16* __restrict__ dst,
                             int R, int C) {
  __shared__ float tile[32][33];
  const int tid = threadIdx.x;
  const int r0 = blockIdx.y * 32, c0 = blockIdx.x * 32;
  const int lr = tid >> 5, lc = tid & 31;
#pragma unroll
  for (int p = 0; p < 4; ++p)
    tile[lr + p * 8][lc] = src[(size_t)(r0 + lr + p * 8) * C + c0 + lc];
  __syncthreads();
#pragma unroll
  for (int p = 0; p < 4; ++p)
    dst[(size_t)(c0 + lr + p * 8) * R + r0 + lc] = (__bf16)tile[lc][lr + p * 8];
}

// ---------------- W13[n][j] = sum_k A[n][k]*B[j][k] (bf16 in/out) ------------
__global__ __launch_bounds__(256, 1) void comp_gemm_kernel(
    const __bf16* __restrict__ A, const __bf16* __restrict__ B,
    __bf16* __restrict__ out) {
  const int tid = threadIdx.x, wid = tid >> 6, lane = tid & 63;
  const int lr = lane & 15, lc = lane >> 4;
  const int m0 = blockIdx.x * 32;
  const int c0 = blockIdx.y * 128 + wid * 32;
  const __bf16* ap0 = A + (size_t)(m0 + lr) * 1024 + lc * 8;
  const __bf16* ap1 = ap0 + (size_t)16 * 1024;
  const __bf16* bp = B + (size_t)(c0 + lr) * 1024 + lc * 8;
  f32x4 acc[2][2] = {};
#pragma unroll 8
  for (int k = 0; k < 1024; k += 32) {
    v8bf a0 = *(const v8bf*)(ap0 + k);
    v8bf a1 = *(const v8bf*)(ap1 + k);
#pragma unroll
    for (int f = 0; f < 2; ++f) {
      v8bf b = *(const v8bf*)(bp + (size_t)f * 16 * 1024 + k);
      acc[0][f] = mfma16(a0, b, acc[0][f]);
      acc[1][f] = mfma16(a1, b, acc[1][f]);
    }
  }
  const int cm = lc << 2, cn = lr;
#pragma unroll
  for (int mf = 0; mf < 2; ++mf)
#pragma unroll
    for (int f = 0; f < 2; ++f)
#pragma unroll
      for (int r = 0; r < 4; ++r)
        out[(size_t)(m0 + mf * 16 + cm + r) * 1024 + c0 + f * 16 + cn] =
            (__bf16)acc[mf][f][r];
}

// ---------------- b13[n] = Wt1s[n]·bt3 ; b1i2[n] = Wt1s[n]·bi2 ---------------
__global__ void bias_comp_kernel(const float* __restrict__ Wt1,
                                 const float* __restrict__ bt3,
                                 const float* __restrict__ bi2,
                                 float* __restrict__ b13, float* __restrict__ b1i2) {
  const int n = blockIdx.x * 4 + (threadIdx.x >> 6);
  const int lane = threadIdx.x & 63;
  const float* row = Wt1 + (size_t)n * 2048;
  float v1 = 0.f, v2 = 0.f;
#pragma unroll
  for (int i = 0; i < 16; ++i) {
    int k = lane + i * 64;
    float w = row[k];
    v1 += w * bt3[k];
    v2 += w * bi2[k];
  }
  for (int o = 32; o; o >>= 1) { v1 += __shfl_down(v1, o); v2 += __shfl_down(v2, o); }
  if (lane == 0) { b13[n] = v1; b1i2[n] = v2; }
}

// ---------------- xc[b][t] = x_t @ Wt1x^T + bt1 (v7-proven) ------------------
__global__ __launch_bounds__(512, 1) void xc_gemm_kernel(
    const float* __restrict__ past, const __bf16* __restrict__ w1x,
    const float* __restrict__ bt1, __bf16* __restrict__ xc) {
  const int t = blockIdx.z + 1;
  const int mh = blockIdx.y;
  const int nb = blockIdx.x;
  const int tid = threadIdx.x, wid = tid >> 6, lane = tid & 63;
  const int wm = wid >> 2, wn = wid & 3;
  const int m0 = mh * 64 + wm * 32;
  const int n0 = nb * 512 + wn * 128;
  const int lr = lane & 15, lc = lane >> 4;
  f32x4 acc[2][8] = {};
  const float* a0p = past + ((size_t)(m0 + lr) * 512 + t) * 1024 + lc * 8;
  const float* a1p = a0p + (size_t)16 * 512 * 1024;
  const __bf16* bp = w1x + (size_t)(n0 + lr) * 1024 + lc * 8;
#pragma unroll 4
  for (int k = 0; k < 1024; k += 32) {
    float4 x00 = *(const float4*)(a0p + k);
    float4 x01 = *(const float4*)(a0p + k + 4);
    float4 x10 = *(const float4*)(a1p + k);
    float4 x11 = *(const float4*)(a1p + k + 4);
    v8bf a0 = cvt8(x00, x01), a1 = cvt8(x10, x11);
#pragma unroll
    for (int j = 0; j < 8; ++j) {
      v8bf b = *(const v8bf*)(bp + (size_t)j * 16 * 1024 + k);
      acc[0][j] = mfma16(a0, b, acc[0][j]);
      acc[1][j] = mfma16(a1, b, acc[1][j]);
    }
  }
  const int cm = lc << 2, cn = lr;
#pragma unroll
  for (int f = 0; f < 2; ++f)
#pragma unroll
    for (int j = 0; j < 8; ++j) {
      int n = n0 + j * 16 + cn;
      float bias = bt1[n];
#pragma unroll
      for (int r = 0; r < 4; ++r) {
        int m = m0 + f * 16 + cm + r;
        xc[((size_t)m * 512 + t) * 2048 + n] = (__bf16)(acc[f][j][r] + bias);
      }
    }
}

// ---- act staging (sc0sc1) -> swizzled LDS -----------------------------------
template <int K>
__device__ inline void stage_issue(f32x4* v, const __bf16* src, int tid) {
  constexpr int KC = K / 8;
#pragma unroll
  for (int i = 0; i < K / 128; ++i) {
    int idx = tid + i * 256;
    int row = idx / KC, kc = idx % KC;
    CLOADC(v[i], src + (size_t)row * K + kc * 8);
  }
}
template <int K>
__device__ inline void stage_commit(char* lds, f32x4* v, int tid) {
  constexpr int KC = K / 8;
#pragma unroll
  for (int i = 0; i < K / 128; ++i) {
    int idx = tid + i * 256;
    int row = idx / KC, kc = idx % KC;
    unsigned byte = ((unsigned)(row * K + kc * 8) * 2) ^ ((unsigned)(row & 7) << 4);
    *(f32x4*)(lds + byte) = v[i];
  }
  __syncthreads();
}

// ---- ring GEMM: swizzled LDS act + plain global weight ring (NF=1) ----------
template <int KIT, int PFD, int KSB>
__device__ inline f32x4 ring_run1(const char* ldsa, int k0, const __bf16* wtb,
                                  f32x4 (&rw)[PFD], int lane) {
  const int lr = lane & 15, lc = lane >> 4;
  f32x4 acc = {0.f, 0.f, 0.f, 0.f};
#pragma unroll
  for (int it = 0; it < KIT; ++it) {
    vwait_n((KIT - 1 - it) < (PFD - 1) ? (KIT - 1 - it) : (PFD - 1));
    v8bf b = as8(rw[it % PFD]);
    if (it + PFD < KIT) CLOADP(rw[it % PFD], wtb, (it + PFD) * 64);
    int k = k0 + it * 32 + lc * 8;
    unsigned byte = ((unsigned)(lr * KSB + k) * 2) ^ ((unsigned)(lr & 7) << 4);
    v8bf a = *(const v8bf*)(ldsa + byte);
    acc = mfma16(a, b, acc);
  }
  return acc;
}
template <int PFD>
__device__ inline void ring_pre(const __bf16* wtb, f32x4 (&rw)[PFD]) {
#pragma unroll
  for (int j = 0; j < PFD; ++j) CLOADP(rw[j], wtb, j * 64);
}

// ---- LDS act + LDS weights ([kb][32][8]) ------------------------------------
__device__ inline f32x4 gemm_aa16(const char* ldsa, int k0, const char* ldsw,
                                  int kb0, int col, int lane) {
  const int lr = lane & 15, lc = lane >> 4;
  f32x4 acc = {0.f, 0.f, 0.f, 0.f};
#pragma unroll
  for (int it = 0; it < 16; ++it) {
    int k = k0 + it * 32 + lc * 8;
    unsigned abyte = ((unsigned)(lr * 1024 + k) * 2) ^ ((unsigned)(lr & 7) << 4);
    v8bf a = *(const v8bf*)(ldsa + abyte);
    v8bf b = *(const v8bf*)(ldsw + (size_t)((kb0 + it * 4 + lc) * 32 + col) * 16);
    acc = mfma16(a, b, acc);
  }
  return acc;
}

// ---------------- persistent recurrence --------------------------------------
__global__ __launch_bounds__(256, 1) void recurrent_kernel(
    const __bf16* __restrict__ wWi1, const __bf16* __restrict__ wWi2,
    const __bf16* __restrict__ wW13, const __bf16* __restrict__ wW1i2,
    const __bf16* __restrict__ wWt2, const __bf16* __restrict__ wWt3,
    const __bf16* __restrict__ x0bf,
    __bf16* __restrict__ z1, __bf16* __restrict__ z2,
    const float* __restrict__ bi1, const float* __restrict__ bi2,
    const float* __restrict__ bt2, const float* __restrict__ bt3,
    const float* __restrict__ b13, const float* __restrict__ b1i2,
    float* __restrict__ out, unsigned* __restrict__ flags) {
  __shared__ alignas(16) char actbuf[65536];   // [16][K<=2048] swizzled acts
  __shared__ alignas(16) char wt3buf[65536];   // Wt3 slice [kb=128][32][8]
  __shared__ alignas(16) char scratch[4096];   // tpose (A) / red+fin (B,C)
  __shared__ int s_dead;
  const int bid = blockIdx.x;
  const int g = bid >> 5, s = bid & 31;
  const int tid = threadIdx.x, wid = tid >> 6, lane = tid & 63;
  const int lr = lane & 15, lc = lane >> 4;
  const int cm = lc << 2, cn = lr;
  const int wn = wid & 1, wk = wid >> 1;
  const int b0 = g * 16;
  const int rp = s & 3;
  if (tid == 0) s_dead = 0;

  unsigned* fA = flags + g * 64;
  unsigned* fB = fA + 32;
  const __bf16* xc = (const __bf16*)out;
  __bf16* tposeb = (__bf16*)scratch;
  float* red = (float*)scratch;
  float* fin = (float*)(scratch + 2048);

  // stage full Wt3 slice (cols s*32..+32, K=1024) -> [kb=128][32][8]
  {
    const __bf16* wg = wWt3 + (size_t)s * 32 * 1024;
    for (int idx = tid; idx < 4096; idx += 256) {
      int kb = idx >> 5, c = idx & 31;
      *(f32x4*)(wt3buf + (size_t)idx * 16) = *(const f32x4*)(wg + (size_t)c * 1024 + kb * 8);
    }
  }

  const int nBC = s * 32 + wn * 16 + cn;
  const int nA = s * 64 + wid * 16 + cn;
  const float bB = bt2[nBC], bCt = bt3[nBC];
  const float bI1 = bi1[nBC], bC0 = bi2[nBC];
  const float bA13 = b13[nA], bA1i2 = b1i2[nA];

  // coalesced store: fin [16][32] fp32 -> bf16 pairs, 4 replicas
  auto storeZ2 = [&](__bf16* base) {
    int row = tid >> 4, col = (tid * 2) & 31;
    unsigned d = bfb(fin[row * 32 + col]) | (bfb(fin[row * 32 + col + 1]) << 16);
#pragma unroll
    for (int rep = 0; rep < 4; ++rep) {
      __bf16* p = base + (size_t)rep * REP2 + (size_t)(b0 + row) * 1024 + s * 32 + col;
      asm volatile("global_store_dword %0, %1, off sc0 sc1" :: "v"(p), "v"(d) : "memory");
    }
  };
  auto storeOut = [&](int tt) {
    int row = tid >> 4, col = (tid * 2) & 31;
    float2 o; o.x = fin[row * 32 + col]; o.y = fin[row * 32 + col + 1];
    *(float2*)(out + (size_t)(b0 + row) * 524288 + (size_t)tt * 1024 + s * 32 + col) = o;
  };

  // ---- init-B: h0 = silu(x0 @ Wi1^T + bi1) -> z2 buf0 ----
  {
    f32x4 sv[8];
    stage_issue<1024>(sv, x0bf + (size_t)b0 * 1024, tid);
    f32x4 rw[8];
    const __bf16* wtb = wWi1 + (size_t)(nBC - cn + lr) * 1024 + wk * 512 + lc * 8;
    ring_pre<8>(wtb, rw);
    vwait<0>();
    stage_commit<1024>(actbuf, sv, tid);
    f32x4 acc = ring_run1<16, 8, 1024>(actbuf, wk * 512, wtb, rw, lane);
    if (wk) {
#pragma unroll
      for (int r = 0; r < 4; ++r) red[wn * 256 + (cm + r) * 16 + cn] = acc[r];
    }
    __syncthreads();
    if (!wk) {
#pragma unroll
      for (int r = 0; r < 4; ++r)
        fin[(cm + r) * 32 + wn * 16 + cn] =
            silu_f(acc[r] + red[wn * 256 + (cm + r) * 16 + cn] + bI1);
    }
    __syncthreads();
    storeZ2(z2);  // buf 0
    release(fB, s, 1u);
  }

  for (int t = 1; t < 512; ++t) {
    // ---- A_t: z1 = silu(W(t)·z2_{t-1} + bA + xc[t]) ----
    {
      const __bf16* wtbA = (t == 1 ? wW1i2 : wW13) +
                           (size_t)(s * 64 + wid * 16 + lr) * 1024 + lc * 8;
      const float bAv = (t == 1) ? bA1i2 : bA13;
      unsigned xcu[4];
#pragma unroll
      for (int r = 0; r < 4; ++r) {
        const __bf16* p = xc + ((size_t)(b0 + cm + r) * 512 + t) * 2048 + nA;
        asm volatile("global_load_ushort %0, %1, off sc0 sc1" : "=v"(xcu[r]) : "v"(p));
      }
      f32x4 rw[12];
      ring_pre<12>(wtbA, rw);
      poll32(fB, (unsigned)t, &s_dead);
      f32x4 sv[8];
      stage_issue<1024>(sv, z2 + ((size_t)((t - 1) & 1) * 4 + rp) * REP2 +
                                (size_t)b0 * 1024, tid);
      vwait<0>();
      stage_commit<1024>(actbuf, sv, tid);
      f32x4 acc = ring_run1<32, 12, 1024>(actbuf, 0, wtbA, rw, lane);
#pragma unroll
      for (int r = 0; r < 4; ++r) {
        float xv = __uint_as_float(xcu[r] << 16);
        tposeb[(cm + r) * 64 + wid * 16 + cn] = (__bf16)silu_f(acc[r] + xv + bAv);
      }
      __syncthreads();
      {
        int row = tid >> 4, col = (tid * 4) & 63;
        unsigned long long d = *(const unsigned long long*)(tposeb + row * 64 + col);
#pragma unroll
        for (int rep = 0; rep < 4; ++rep) {
          __bf16* p = z1 + (size_t)rep * REP1 + (size_t)(b0 + row) * 2048 + s * 64 + col;
          asm volatile("global_store_dwordx2 %0, %1, off sc0 sc1" :: "v"(p), "v"(d) : "memory");
        }
      }
      release(fA, s, (unsigned)t);
    }
    // ---- C_{t-1} (off-path): out[:,t-1,:] from staged z2_{t-1} ----
    {
      f32x4 acc;
      if (t == 1) {
        const __bf16* wtbC = wWi2 + (size_t)(nBC - cn + lr) * 1024 + wk * 512 + lc * 8;
        f32x4 rw[8];
        ring_pre<8>(wtbC, rw);
        acc = ring_run1<16, 8, 1024>(actbuf, wk * 512, wtbC, rw, lane);
      } else {
        acc = gemm_aa16(actbuf, wk * 512, wt3buf, wk * 64, wn * 16 + lr, lane);
      }
      const float bCv = (t == 1) ? bC0 : bCt;
      if (wk) {
#pragma unroll
        for (int r = 0; r < 4; ++r) red[wn * 256 + (cm + r) * 16 + cn] = acc[r];
      }
      __syncthreads();
      if (!wk) {
#pragma unroll
        for (int r = 0; r < 4; ++r)
          fin[(cm + r) * 32 + wn * 16 + cn] =
              acc[r] + red[wn * 256 + (cm + r) * 16 + cn] + bCv;
      }
      __syncthreads();
      storeOut(t - 1);
    }
    // ---- B_t: z2[t&1] = silu(z1 @ Wt2^T + bt2) ----
    {
      const __bf16* wtbB = wWt2 + (size_t)(nBC - cn + lr) * 2048 + wk * 1024 + lc * 8;
      f32x4 rw[12];
      ring_pre<12>(wtbB, rw);
      poll32(fA, (unsigned)t, &s_dead);
      f32x4 sv[16];
      stage_issue<2048>(sv, z1 + (size_t)rp * REP1 + (size_t)b0 * 2048, tid);
      vwait<0>();
      stage_commit<2048>(actbuf, sv, tid);
      f32x4 acc = ring_run1<32, 12, 2048>(actbuf, wk * 1024, wtbB, rw, lane);
      if (wk) {
#pragma unroll
        for (int r = 0; r < 4; ++r) red[wn * 256 + (cm + r) * 16 + cn] = acc[r];
      }
      __syncthreads();
      if (!wk) {
#pragma unroll
        for (int r = 0; r < 4; ++r)
          fin[(cm + r) * 32 + wn * 16 + cn] =
              silu_f(acc[r] + red[wn * 256 + (cm + r) * 16 + cn] + bB);
      }
      __syncthreads();
      storeZ2(z2 + (size_t)(t & 1) * 4 * REP2);
      release(fB, s, (unsigned)(t + 1));
    }
  }
  // ---- epilogue: C_511 -> out[:,511,:] ----
  {
    poll32(fB, 512u, &s_dead);
    f32x4 sv[8];
    stage_issue<1024>(sv, z2 + ((size_t)1 * 4 + rp) * REP2 + (size_t)b0 * 1024, tid);
    vwait<0>();
    stage_commit<1024>(actbuf, sv, tid);
    f32x4 acc = gemm_aa16(actbuf, wk * 512, wt3buf, wk * 64, wn * 16 + lr, lane);
    if (wk) {
#pragma unroll
      for (int r = 0; r < 4; ++r) red[wn * 256 + (cm + r) * 16 + cn] = acc[r];
    }
    __syncthreads();
    if (!wk) {
#pragma unroll
      for (int r = 0; r < 4; ++r)
        fin[(cm + r) * 32 + wn * 16 + cn] =
            acc[r] + red[wn * 256 + (cm + r) * 16 + cn] + bCt;
    }
    __syncthreads();
    storeOut(511);
  }
}

// ---------------- host launcher ----------------------------------------------
extern "C" void kernel_launch(void* const* d_in, const int* in_sizes, int n_in,
                              void* d_out, int out_size, void* d_ws, size_t ws_size,
                              hipStream_t stream) {
  (void)in_sizes; (void)n_in; (void)out_size; (void)ws_size;
  const float* past = (const float*)d_in[0];
  const float* Wi1 = (const float*)d_in[1];
  const float* bi1 = (const float*)d_in[2];
  const float* Wi2 = (const float*)d_in[3];
  const float* bi2 = (const float*)d_in[4];
  const float* Wt1 = (const float*)d_in[5];
  const float* bt1 = (const float*)d_in[6];
  const float* Wt2 = (const float*)d_in[7];
  const float* bt2 = (const float*)d_in[8];
  const float* Wt3 = (const float*)d_in[9];
  const float* bt3 = (const float*)d_in[10];
  float* out = (float*)d_out;

  char* ws = (char*)d_ws;
  size_t off = 0;
  unsigned* flags = (unsigned*)(ws + off); off += 4096;
  __bf16* wWi1 = (__bf16*)(ws + off);  off += (size_t)1024 * 1024 * 2;
  __bf16* wWi2 = (__bf16*)(ws + off);  off += (size_t)1024 * 1024 * 2;
  __bf16* wWt1s = (__bf16*)(ws + off); off += (size_t)2048 * 1024 * 2;
  __bf16* wWt1x = (__bf16*)(ws + off); off += (size_t)2048 * 1024 * 2;
  __bf16* wWt2 = (__bf16*)(ws + off);  off += (size_t)1024 * 2048 * 2;
  __bf16* wWt3 = (__bf16*)(ws + off);  off += (size_t)1024 * 1024 * 2;
  __bf16* wWt3T = (__bf16*)(ws + off); off += (size_t)1024 * 1024 * 2;
  __bf16* wWi2T = (__bf16*)(ws + off); off += (size_t)1024 * 1024 * 2;
  __bf16* wW13 = (__bf16*)(ws + off);  off += (size_t)2048 * 1024 * 2;
  __bf16* wW1i2 = (__bf16*)(ws + off); off += (size_t)2048 * 1024 * 2;
  float* b13 = (float*)(ws + off);     off += 2048 * 4;
  float* b1i2 = (float*)(ws + off);    off += 2048 * 4;
  __bf16* x0bf = (__bf16*)(ws + off);  off += (size_t)128 * 1024 * 2;
  __bf16* z1 = (__bf16*)(ws + off);    off += (size_t)4 * REP1 * 2;
  __bf16* z2 = (__bf16*)(ws + off);    off += (size_t)8 * REP2 * 2;

  hipMemsetAsync(flags, 0, 4096, stream);

  auto cvt = [&](const float* s, __bf16* d, int rows, int cols, int log2c,
                 int sstride, int soff) {
    int total8 = rows * cols / 8;
    cvt_kernel<<<dim3((total8 + 255) / 256), dim3(256), 0, stream>>>(
        s, d, total8, log2c, sstride, soff);
  };
  cvt(Wi1, wWi1, 1024, 1024, 10, 1024, 0);
  cvt(Wi2, wWi2, 1024, 1024, 10, 1024, 0);
  cvt(Wt1, wWt1s, 2048, 1024, 10, 2048, 0);
  cvt(Wt1, wWt1x, 2048, 1024, 10, 2048, 1024);
  cvt(Wt2, wWt2, 1024, 2048, 11, 2048, 0);
  cvt(Wt3, wWt3, 1024, 1024, 10, 1024, 0);
  cvt(past, x0bf, 128, 1024, 10, 512 * 1024, 0);

  tpose_kernel<<<dim3(32, 32), dim3(256), 0, stream>>>(Wt3, wWt3T, 1024, 1024);
  tpose_kernel<<<dim3(32, 32), dim3(256), 0, stream>>>(Wi2, wWi2T, 1024, 1024);
  comp_gemm_kernel<<<dim3(64, 8), dim3(256), 0, stream>>>(wWt1s, wWt3T, wW13);
  comp_gemm_kernel<<<dim3(64, 8), dim3(256), 0, stream>>>(wWt1s, wWi2T, wW1i2);
  bias_comp_kernel<<<dim3(512), dim3(256), 0, stream>>>(Wt1, bt3, bi2, b13, b1i2);

  xc_gemm_kernel<<<dim3(4, 2, 511), dim3(512), 0, stream>>>(
      past, wWt1x, bt1, (__bf16*)d_out);

  recurrent_kernel<<<dim3(256), dim3(256), 0, stream>>>(
      wWi1, wWi2, wW13, wW1i2, wWt2, wWt3, x0bf, z1, z2,
      bi1, bi2, bt2, bt3, b13, b1i2, out, flags);
}

// Round 14
// 8005.768 us; speedup vs baseline: 2.7016x; 1.0126x over previous
//
#include <hip/hip_runtime.h>
#include <hip/hip_bf16.h>

// TrueMarkovChain v14: v12 (known-good, 8.1ms) + ONE change: PFD 12->16 on the
// A/B weight rings. v13's combo (PFD20 persistent rings + cross-iteration
// hoists + plain xc) SIGABRT'd and could not be attributed -> reverted.
// Structure: z1_t = silu(W13·z2_{t-1}+b13+xc_t) (W13=Wt1s@Wt3 composed);
// A->B 2 hops/step; C off-path (Wt3 LDS-pinned); z2 double-buffered; 4x act
// replicas; sc0sc1 exchange + coalesced stores; guarded polls + dead-latch.

typedef __bf16 v8bf __attribute__((ext_vector_type(8)));
typedef float f32x4 __attribute__((ext_vector_type(4)));
typedef unsigned u32x4 __attribute__((ext_vector_type(4)));

#define REP1 (128 * 2048)
#define REP2 (128 * 1024)

__device__ inline f32x4 mfma16(v8bf a, v8bf b, f32x4 c) {
  return __builtin_amdgcn_mfma_f32_16x16x32_bf16(a, b, c, 0, 0, 0);
}
__device__ inline float silu_f(float x) { return x / (1.f + __expf(-x)); }
__device__ inline v8bf as8(f32x4 x) { union { f32x4 f; v8bf b; } u; u.f = x; return u.b; }
__device__ inline v8bf cvt8(float4 a, float4 b) {
  v8bf v;
  v[0] = (__bf16)a.x; v[1] = (__bf16)a.y; v[2] = (__bf16)a.z; v[3] = (__bf16)a.w;
  v[4] = (__bf16)b.x; v[5] = (__bf16)b.y; v[6] = (__bf16)b.z; v[7] = (__bf16)b.w;
  return v;
}
__device__ inline unsigned bfb(float v) {
  __bf16 b = (__bf16)v; unsigned short u; __builtin_memcpy(&u, &b, 2); return (unsigned)u;
}

#define CLOADP(dst, base, boff)                                        \
  asm volatile("global_load_dwordx4 %0, %1, off offset:%2"             \
               : "=v"(dst) : "v"(base), "n"(boff))
#define CLOADC(dst, base)                                              \
  asm volatile("global_load_dwordx4 %0, %1, off sc0 sc1" : "=v"(dst) : "v"(base))

template <int N> __device__ inline void vwait() {
  asm volatile("s_waitcnt vmcnt(%0)" :: "n"(N) : "memory");
  __builtin_amdgcn_sched_barrier(0);
}
__device__ inline void vwait_n(int n) {
  switch (n) {
    case 0: vwait<0>(); break;   case 1: vwait<1>(); break;
    case 2: vwait<2>(); break;   case 3: vwait<3>(); break;
    case 4: vwait<4>(); break;   case 5: vwait<5>(); break;
    case 6: vwait<6>(); break;   case 7: vwait<7>(); break;
    case 8: vwait<8>(); break;   case 9: vwait<9>(); break;
    case 10: vwait<10>(); break; case 11: vwait<11>(); break;
    case 12: vwait<12>(); break; case 13: vwait<13>(); break;
    case 14: vwait<14>(); break; default: vwait<15>(); break;
  }
}

__device__ inline void poll32(const unsigned* f, unsigned tgt, int* dead) {
  if (threadIdx.x < 8 && !*dead) {
    const unsigned* p = f + threadIdx.x * 4;
    int guard = 0;
    while (true) {
      u32x4 v;
      asm volatile("global_load_dwordx4 %0, %1, off sc0 sc1\n\ts_waitcnt vmcnt(0)"
                   : "=v"(v) : "v"(p) : "memory");
      if (v[0] >= tgt && v[1] >= tgt && v[2] >= tgt && v[3] >= tgt) break;
      if (++guard > (1 << 18)) { *dead = 1; break; }
      __builtin_amdgcn_s_sleep(1);
    }
  }
  __syncthreads();
}
__device__ inline void release(unsigned* f, int slot, unsigned v) {
  asm volatile("s_waitcnt vmcnt(0)" ::: "memory");
  __syncthreads();
  if (threadIdx.x == 0)
    asm volatile("global_store_dword %0, %1, off sc0 sc1" :: "v"(f + slot), "v"(v) : "memory");
}

// ---------------- fp32 -> bf16 strided converter -----------------------------
__global__ void cvt_kernel(const float* __restrict__ src, __bf16* __restrict__ dst,
                           int total8, int log2cols, int sstride, int soff) {
  int i = blockIdx.x * 256 + threadIdx.x;
  if (i >= total8) return;
  long long e = (long long)i * 8;
  int r = (int)(e >> log2cols);
  int c = (int)(e & ((1LL << log2cols) - 1));
  const float* s = src + (size_t)r * sstride + soff + c;
  float4 f0 = *(const float4*)(s);
  float4 f1 = *(const float4*)(s + 4);
  *(v8bf*)(dst + e) = cvt8(f0, f1);
}

// ---------------- fp32 (R x C) -> bf16 transposed (C x R) --------------------
__global__ void tpose_kernel(const float* __restrict__ src, __bf16* __restrict__ dst,
                             int R, int C) {
  __shared__ float tile[32][33];
  const int tid = threadIdx.x;
  const int r0 = blockIdx.y * 32, c0 = blockIdx.x * 32;
  const int lr = tid >> 5, lc = tid & 31;
#pragma unroll
  for (int p = 0; p < 4; ++p)
    tile[lr + p * 8][lc] = src[(size_t)(r0 + lr + p * 8) * C + c0 + lc];
  __syncthreads();
#pragma unroll
  for (int p = 0; p < 4; ++p)
    dst[(size_t)(c0 + lr + p * 8) * R + r0 + lc] = (__bf16)tile[lc][lr + p * 8];
}

// ---------------- W13[n][j] = sum_k A[n][k]*B[j][k] (bf16 in/out) ------------
__global__ __launch_bounds__(256, 1) void comp_gemm_kernel(
    const __bf16* __restrict__ A, const __bf16* __restrict__ B,
    __bf16* __restrict__ out) {
  const int tid = threadIdx.x, wid = tid >> 6, lane = tid & 63;
  const int lr = lane & 15, lc = lane >> 4;
  const int m0 = blockIdx.x * 32;
  const int c0 = blockIdx.y * 128 + wid * 32;
  const __bf16* ap0 = A + (size_t)(m0 + lr) * 1024 + lc * 8;
  const __bf16* ap1 = ap0 + (size_t)16 * 1024;
  const __bf16* bp = B + (size_t)(c0 + lr) * 1024 + lc * 8;
  f32x4 acc[2][2] = {};
#pragma unroll 8
  for (int k = 0; k < 1024; k += 32) {
    v8bf a0 = *(const v8bf*)(ap0 + k);
    v8bf a1 = *(const v8bf*)(ap1 + k);
#pragma unroll
    for (int f = 0; f < 2; ++f) {
      v8bf b = *(const v8bf*)(bp + (size_t)f * 16 * 1024 + k);
      acc[0][f] = mfma16(a0, b, acc[0][f]);
      acc[1][f] = mfma16(a1, b, acc[1][f]);
    }
  }
  const int cm = lc << 2, cn = lr;
#pragma unroll
  for (int mf = 0; mf < 2; ++mf)
#pragma unroll
    for (int f = 0; f < 2; ++f)
#pragma unroll
      for (int r = 0; r < 4; ++r)
        out[(size_t)(m0 + mf * 16 + cm + r) * 1024 + c0 + f * 16 + cn] =
            (__bf16)acc[mf][f][r];
}

// ---------------- b13[n] = Wt1s[n]·bt3 ; b1i2[n] = Wt1s[n]·bi2 ---------------
__global__ void bias_comp_kernel(const float* __restrict__ Wt1,
                                 const float* __restrict__ bt3,
                                 const float* __restrict__ bi2,
                                 float* __restrict__ b13, float* __restrict__ b1i2) {
  const int n = blockIdx.x * 4 + (threadIdx.x >> 6);
  const int lane = threadIdx.x & 63;
  const float* row = Wt1 + (size_t)n * 2048;
  float v1 = 0.f, v2 = 0.f;
#pragma unroll
  for (int i = 0; i < 16; ++i) {
    int k = lane + i * 64;
    float w = row[k];
    v1 += w * bt3[k];
    v2 += w * bi2[k];
  }
  for (int o = 32; o; o >>= 1) { v1 += __shfl_down(v1, o); v2 += __shfl_down(v2, o); }
  if (lane == 0) { b13[n] = v1; b1i2[n] = v2; }
}

// ---------------- xc[b][t] = x_t @ Wt1x^T + bt1 (v7-proven) ------------------
__global__ __launch_bounds__(512, 1) void xc_gemm_kernel(
    const float* __restrict__ past, const __bf16* __restrict__ w1x,
    const float* __restrict__ bt1, __bf16* __restrict__ xc) {
  const int t = blockIdx.z + 1;
  const int mh = blockIdx.y;
  const int nb = blockIdx.x;
  const int tid = threadIdx.x, wid = tid >> 6, lane = tid & 63;
  const int wm = wid >> 2, wn = wid & 3;
  const int m0 = mh * 64 + wm * 32;
  const int n0 = nb * 512 + wn * 128;
  const int lr = lane & 15, lc = lane >> 4;
  f32x4 acc[2][8] = {};
  const float* a0p = past + ((size_t)(m0 + lr) * 512 + t) * 1024 + lc * 8;
  const float* a1p = a0p + (size_t)16 * 512 * 1024;
  const __bf16* bp = w1x + (size_t)(n0 + lr) * 1024 + lc * 8;
#pragma unroll 4
  for (int k = 0; k < 1024; k += 32) {
    float4 x00 = *(const float4*)(a0p + k);
    float4 x01 = *(const float4*)(a0p + k + 4);
    float4 x10 = *(const float4*)(a1p + k);
    float4 x11 = *(const float4*)(a1p + k + 4);
    v8bf a0 = cvt8(x00, x01), a1 = cvt8(x10, x11);
#pragma unroll
    for (int j = 0; j < 8; ++j) {
      v8bf b = *(const v8bf*)(bp + (size_t)j * 16 * 1024 + k);
      acc[0][j] = mfma16(a0, b, acc[0][j]);
      acc[1][j] = mfma16(a1, b, acc[1][j]);
    }
  }
  const int cm = lc << 2, cn = lr;
#pragma unroll
  for (int f = 0; f < 2; ++f)
#pragma unroll
    for (int j = 0; j < 8; ++j) {
      int n = n0 + j * 16 + cn;
      float bias = bt1[n];
#pragma unroll
      for (int r = 0; r < 4; ++r) {
        int m = m0 + f * 16 + cm + r;
        xc[((size_t)m * 512 + t) * 2048 + n] = (__bf16)(acc[f][j][r] + bias);
      }
    }
}

// ---- act staging (sc0sc1) -> swizzled LDS -----------------------------------
template <int K>
__device__ inline void stage_issue(f32x4* v, const __bf16* src, int tid) {
  constexpr int KC = K / 8;
#pragma unroll
  for (int i = 0; i < K / 128; ++i) {
    int idx = tid + i * 256;
    int row = idx / KC, kc = idx % KC;
    CLOADC(v[i], src + (size_t)row * K + kc * 8);
  }
}
template <int K>
__device__ inline void stage_commit(char* lds, f32x4* v, int tid) {
  constexpr int KC = K / 8;
#pragma unroll
  for (int i = 0; i < K / 128; ++i) {
    int idx = tid + i * 256;
    int row = idx / KC, kc = idx % KC;
    unsigned byte = ((unsigned)(row * K + kc * 8) * 2) ^ ((unsigned)(row & 7) << 4);
    *(f32x4*)(lds + byte) = v[i];
  }
  __syncthreads();
}

// ---- ring GEMM: swizzled LDS act + plain global weight ring (NF=1) ----------
template <int KIT, int PFD, int KSB>
__device__ inline f32x4 ring_run1(const char* ldsa, int k0, const __bf16* wtb,
                                  f32x4 (&rw)[PFD], int lane) {
  const int lr = lane & 15, lc = lane >> 4;
  f32x4 acc = {0.f, 0.f, 0.f, 0.f};
#pragma unroll
  for (int it = 0; it < KIT; ++it) {
    vwait_n((KIT - 1 - it) < (PFD - 1) ? (KIT - 1 - it) : (PFD - 1));
    v8bf b = as8(rw[it % PFD]);
    if (it + PFD < KIT) CLOADP(rw[it % PFD], wtb, (it + PFD) * 64);
    int k = k0 + it * 32 + lc * 8;
    unsigned byte = ((unsigned)(lr * KSB + k) * 2) ^ ((unsigned)(lr & 7) << 4);
    v8bf a = *(const v8bf*)(ldsa + byte);
    acc = mfma16(a, b, acc);
  }
  return acc;
}
template <int PFD>
__device__ inline void ring_pre(const __bf16* wtb, f32x4 (&rw)[PFD]) {
#pragma unroll
  for (int j = 0; j < PFD; ++j) CLOADP(rw[j], wtb, j * 64);
}

// ---- LDS act + LDS weights ([kb][32][8]) ------------------------------------
__device__ inline f32x4 gemm_aa16(const char* ldsa, int k0, const char* ldsw,
                                  int kb0, int col, int lane) {
  const int lr = lane & 15, lc = lane >> 4;
  f32x4 acc = {0.f, 0.f, 0.f, 0.f};
#pragma unroll
  for (int it = 0; it < 16; ++it) {
    int k = k0 + it * 32 + lc * 8;
    unsigned abyte = ((unsigned)(lr * 1024 + k) * 2) ^ ((unsigned)(lr & 7) << 4);
    v8bf a = *(const v8bf*)(ldsa + abyte);
    v8bf b = *(const v8bf*)(ldsw + (size_t)((kb0 + it * 4 + lc) * 32 + col) * 16);
    acc = mfma16(a, b, acc);
  }
  return acc;
}

// ---------------- persistent recurrence --------------------------------------
__global__ __launch_bounds__(256, 1) void recurrent_kernel(
    const __bf16* __restrict__ wWi1, const __bf16* __restrict__ wWi2,
    const __bf16* __restrict__ wW13, const __bf16* __restrict__ wW1i2,
    const __bf16* __restrict__ wWt2, const __bf16* __restrict__ wWt3,
    const __bf16* __restrict__ x0bf,
    __bf16* __restrict__ z1, __bf16* __restrict__ z2,
    const float* __restrict__ bi1, const float* __restrict__ bi2,
    const float* __restrict__ bt2, const float* __restrict__ bt3,
    const float* __restrict__ b13, const float* __restrict__ b1i2,
    float* __restrict__ out, unsigned* __restrict__ flags) {
  __shared__ alignas(16) char actbuf[65536];   // [16][K<=2048] swizzled acts
  __shared__ alignas(16) char wt3buf[65536];   // Wt3 slice [kb=128][32][8]
  __shared__ alignas(16) char scratch[4096];   // tpose (A) / red+fin (B,C)
  __shared__ int s_dead;
  const int bid = blockIdx.x;
  const int g = bid >> 5, s = bid & 31;
  const int tid = threadIdx.x, wid = tid >> 6, lane = tid & 63;
  const int lr = lane & 15, lc = lane >> 4;
  const int cm = lc << 2, cn = lr;
  const int wn = wid & 1, wk = wid >> 1;
  const int b0 = g * 16;
  const int rp = s & 3;
  if (tid == 0) s_dead = 0;

  unsigned* fA = flags + g * 64;
  unsigned* fB = fA + 32;
  const __bf16* xc = (const __bf16*)out;
  __bf16* tposeb = (__bf16*)scratch;
  float* red = (float*)scratch;
  float* fin = (float*)(scratch + 2048);

  // stage full Wt3 slice (cols s*32..+32, K=1024) -> [kb=128][32][8]
  {
    const __bf16* wg = wWt3 + (size_t)s * 32 * 1024;
    for (int idx = tid; idx < 4096; idx += 256) {
      int kb = idx >> 5, c = idx & 31;
      *(f32x4*)(wt3buf + (size_t)idx * 16) = *(const f32x4*)(wg + (size_t)c * 1024 + kb * 8);
    }
  }

  const int nBC = s * 32 + wn * 16 + cn;
  const int nA = s * 64 + wid * 16 + cn;
  const float bB = bt2[nBC], bCt = bt3[nBC];
  const float bI1 = bi1[nBC], bC0 = bi2[nBC];
  const float bA13 = b13[nA], bA1i2 = b1i2[nA];

  auto storeZ2 = [&](__bf16* base) {
    int row = tid >> 4, col = (tid * 2) & 31;
    unsigned d = bfb(fin[row * 32 + col]) | (bfb(fin[row * 32 + col + 1]) << 16);
#pragma unroll
    for (int rep = 0; rep < 4; ++rep) {
      __bf16* p = base + (size_t)rep * REP2 + (size_t)(b0 + row) * 1024 + s * 32 + col;
      asm volatile("global_store_dword %0, %1, off sc0 sc1" :: "v"(p), "v"(d) : "memory");
    }
  };
  auto storeOut = [&](int tt) {
    int row = tid >> 4, col = (tid * 2) & 31;
    float2 o; o.x = fin[row * 32 + col]; o.y = fin[row * 32 + col + 1];
    *(float2*)(out + (size_t)(b0 + row) * 524288 + (size_t)tt * 1024 + s * 32 + col) = o;
  };

  // ---- init-B: h0 = silu(x0 @ Wi1^T + bi1) -> z2 buf0 ----
  {
    f32x4 sv[8];
    stage_issue<1024>(sv, x0bf + (size_t)b0 * 1024, tid);
    f32x4 rw[8];
    const __bf16* wtb = wWi1 + (size_t)(nBC - cn + lr) * 1024 + wk * 512 + lc * 8;
    ring_pre<8>(wtb, rw);
    vwait<0>();
    stage_commit<1024>(actbuf, sv, tid);
    f32x4 acc = ring_run1<16, 8, 1024>(actbuf, wk * 512, wtb, rw, lane);
    if (wk) {
#pragma unroll
      for (int r = 0; r < 4; ++r) red[wn * 256 + (cm + r) * 16 + cn] = acc[r];
    }
    __syncthreads();
    if (!wk) {
#pragma unroll
      for (int r = 0; r < 4; ++r)
        fin[(cm + r) * 32 + wn * 16 + cn] =
            silu_f(acc[r] + red[wn * 256 + (cm + r) * 16 + cn] + bI1);
    }
    __syncthreads();
    storeZ2(z2);  // buf 0
    release(fB, s, 1u);
  }

  for (int t = 1; t < 512; ++t) {
    // ---- A_t: z1 = silu(W(t)·z2_{t-1} + bA + xc[t]) ----
    {
      const __bf16* wtbA = (t == 1 ? wW1i2 : wW13) +
                           (size_t)(s * 64 + wid * 16 + lr) * 1024 + lc * 8;
      const float bAv = (t == 1) ? bA1i2 : bA13;
      unsigned xcu[4];
#pragma unroll
      for (int r = 0; r < 4; ++r) {
        const __bf16* p = xc + ((size_t)(b0 + cm + r) * 512 + t) * 2048 + nA;
        asm volatile("global_load_ushort %0, %1, off sc0 sc1" : "=v"(xcu[r]) : "v"(p));
      }
      f32x4 rw[16];
      ring_pre<16>(wtbA, rw);
      poll32(fB, (unsigned)t, &s_dead);
      f32x4 sv[8];
      stage_issue<1024>(sv, z2 + ((size_t)((t - 1) & 1) * 4 + rp) * REP2 +
                                (size_t)b0 * 1024, tid);
      vwait<0>();
      stage_commit<1024>(actbuf, sv, tid);
      f32x4 acc = ring_run1<32, 16, 1024>(actbuf, 0, wtbA, rw, lane);
#pragma unroll
      for (int r = 0; r < 4; ++r) {
        float xv = __uint_as_float(xcu[r] << 16);
        tposeb[(cm + r) * 64 + wid * 16 + cn] = (__bf16)silu_f(acc[r] + xv + bAv);
      }
      __syncthreads();
      {
        int row = tid >> 4, col = (tid * 4) & 63;
        unsigned long long d = *(const unsigned long long*)(tposeb + row * 64 + col);
#pragma unroll
        for (int rep = 0; rep < 4; ++rep) {
          __bf16* p = z1 + (size_t)rep * REP1 + (size_t)(b0 + row) * 2048 + s * 64 + col;
          asm volatile("global_store_dwordx2 %0, %1, off sc0 sc1" :: "v"(p), "v"(d) : "memory");
        }
      }
      release(fA, s, (unsigned)t);
    }
    // ---- C_{t-1} (off-path): out[:,t-1,:] from staged z2_{t-1} ----
    {
      f32x4 acc;
      if (t == 1) {
        const __bf16* wtbC = wWi2 + (size_t)(nBC - cn + lr) * 1024 + wk * 512 + lc * 8;
        f32x4 rw[8];
        ring_pre<8>(wtbC, rw);
        acc = ring_run1<16, 8, 1024>(actbuf, wk * 512, wtbC, rw, lane);
      } else {
        acc = gemm_aa16(actbuf, wk * 512, wt3buf, wk * 64, wn * 16 + lr, lane);
      }
      const float bCv = (t == 1) ? bC0 : bCt;
      if (wk) {
#pragma unroll
        for (int r = 0; r < 4; ++r) red[wn * 256 + (cm + r) * 16 + cn] = acc[r];
      }
      __syncthreads();
      if (!wk) {
#pragma unroll
        for (int r = 0; r < 4; ++r)
          fin[(cm + r) * 32 + wn * 16 + cn] =
              acc[r] + red[wn * 256 + (cm + r) * 16 + cn] + bCv;
      }
      __syncthreads();
      storeOut(t - 1);
    }
    // ---- B_t: z2[t&1] = silu(z1 @ Wt2^T + bt2) ----
    {
      const __bf16* wtbB = wWt2 + (size_t)(nBC - cn + lr) * 2048 + wk * 1024 + lc * 8;
      f32x4 rw[16];
      ring_pre<16>(wtbB, rw);
      poll32(fA, (unsigned)t, &s_dead);
      f32x4 sv[16];
      stage_issue<2048>(sv, z1 + (size_t)rp * REP1 + (size_t)b0 * 2048, tid);
      vwait<0>();
      stage_commit<2048>(actbuf, sv, tid);
      f32x4 acc = ring_run1<32, 16, 2048>(actbuf, wk * 1024, wtbB, rw, lane);
      if (wk) {
#pragma unroll
        for (int r = 0; r < 4; ++r) red[wn * 256 + (cm + r) * 16 + cn] = acc[r];
      }
      __syncthreads();
      if (!wk) {
#pragma unroll
        for (int r = 0; r < 4; ++r)
          fin[(cm + r) * 32 + wn * 16 + cn] =
              silu_f(acc[r] + red[wn * 256 + (cm + r) * 16 + cn] + bB);
      }
      __syncthreads();
      storeZ2(z2 + (size_t)(t & 1) * 4 * REP2);
      release(fB, s, (unsigned)(t + 1));
    }
  }
  // ---- epilogue: C_511 -> out[:,511,:] ----
  {
    poll32(fB, 512u, &s_dead);
    f32x4 sv[8];
    stage_issue<1024>(sv, z2 + ((size_t)1 * 4 + rp) * REP2 + (size_t)b0 * 1024, tid);
    vwait<0>();
    stage_commit<1024>(actbuf, sv, tid);
    f32x4 acc = gemm_aa16(actbuf, wk * 512, wt3buf, wk * 64, wn * 16 + lr, lane);
    if (wk) {
#pragma unroll
      for (int r = 0; r < 4; ++r) red[wn * 256 + (cm + r) * 16 + cn] = acc[r];
    }
    __syncthreads();
    if (!wk) {
#pragma unroll
      for (int r = 0; r < 4; ++r)
        fin[(cm + r) * 32 + wn * 16 + cn] =
            acc[r] + red[wn * 256 + (cm + r) * 16 + cn] + bCt;
    }
    __syncthreads();
    storeOut(511);
  }
}

// ---------------- host launcher ----------------------------------------------
extern "C" void kernel_launch(void* const* d_in, const int* in_sizes, int n_in,
                              void* d_out, int out_size, void* d_ws, size_t ws_size,
                              hipStream_t stream) {
  (void)in_sizes; (void)n_in; (void)out_size; (void)ws_size;
  const float* past = (const float*)d_in[0];
  const float* Wi1 = (const float*)d_in[1];
  const float* bi1 = (const float*)d_in[2];
  const float* Wi2 = (const float*)d_in[3];
  const float* bi2 = (const float*)d_in[4];
  const float* Wt1 = (const float*)d_in[5];
  const float* bt1 = (const float*)d_in[6];
  const float* Wt2 = (const float*)d_in[7];
  const float* bt2 = (const float*)d_in[8];
  const float* Wt3 = (const float*)d_in[9];
  const float* bt3 = (const float*)d_in[10];
  float* out = (float*)d_out;

  char* ws = (char*)d_ws;
  size_t off = 0;
  unsigned* flags = (unsigned*)(ws + off); off += 4096;
  __bf16* wWi1 = (__bf16*)(ws + off);  off += (size_t)1024 * 1024 * 2;
  __bf16* wWi2 = (__bf16*)(ws + off);  off += (size_t)1024 * 1024 * 2;
  __bf16* wWt1s = (__bf16*)(ws + off); off += (size_t)2048 * 1024 * 2;
  __bf16* wWt1x = (__bf16*)(ws + off); off += (size_t)2048 * 1024 * 2;
  __bf16* wWt2 = (__bf16*)(ws + off);  off += (size_t)1024 * 2048 * 2;
  __bf16* wWt3 = (__bf16*)(ws + off);  off += (size_t)1024 * 1024 * 2;
  __bf16* wWt3T = (__bf16*)(ws + off); off += (size_t)1024 * 1024 * 2;
  __bf16* wWi2T = (__bf16*)(ws + off); off += (size_t)1024 * 1024 * 2;
  __bf16* wW13 = (__bf16*)(ws + off);  off += (size_t)2048 * 1024 * 2;
  __bf16* wW1i2 = (__bf16*)(ws + off); off += (size_t)2048 * 1024 * 2;
  float* b13 = (float*)(ws + off);     off += 2048 * 4;
  float* b1i2 = (float*)(ws + off);    off += 2048 * 4;
  __bf16* x0bf = (__bf16*)(ws + off);  off += (size_t)128 * 1024 * 2;
  __bf16* z1 = (__bf16*)(ws + off);    off += (size_t)4 * REP1 * 2;
  __bf16* z2 = (__bf16*)(ws + off);    off += (size_t)8 * REP2 * 2;

  hipMemsetAsync(flags, 0, 4096, stream);

  auto cvt = [&](const float* s, __bf16* d, int rows, int cols, int log2c,
                 int sstride, int soff) {
    int total8 = rows * cols / 8;
    cvt_kernel<<<dim3((total8 + 255) / 256), dim3(256), 0, stream>>>(
        s, d, total8, log2c, sstride, soff);
  };
  cvt(Wi1, wWi1, 1024, 1024, 10, 1024, 0);
  cvt(Wi2, wWi2, 1024, 1024, 10, 1024, 0);
  cvt(Wt1, wWt1s, 2048, 1024, 10, 2048, 0);
  cvt(Wt1, wWt1x, 2048, 1024, 10, 2048, 1024);
  cvt(Wt2, wWt2, 1024, 2048, 11, 2048, 0);
  cvt(Wt3, wWt3, 1024, 1024, 10, 1024, 0);
  cvt(past, x0bf, 128, 1024, 10, 512 * 1024, 0);

  tpose_kernel<<<dim3(32, 32), dim3(256), 0, stream>>>(Wt3, wWt3T, 1024, 1024);
  tpose_kernel<<<dim3(32, 32), dim3(256), 0, stream>>>(Wi2, wWi2T, 1024, 1024);
  comp_gemm_kernel<<<dim3(64, 8), dim3(256), 0, stream>>>(wWt1s, wWt3T, wW13);
  comp_gemm_kernel<<<dim3(64, 8), dim3(256), 0, stream>>>(wWt1s, wWi2T, wW1i2);
  bias_comp_kernel<<<dim3(512), dim3(256), 0, stream>>>(Wt1, bt3, bi2, b13, b1i2);

  xc_gemm_kernel<<<dim3(4, 2, 511), dim3(512), 0, stream>>>(
      past, wWt1x, bt1, (__bf16*)d_out);

  recurrent_kernel<<<dim3(256), dim3(256), 0, stream>>>(
      wWi1, wWi2, wW13, wW1i2, wWt2, wWt3, x0bf, z1, z2,
      bi1, bi2, bt2, bt3, b13, b1i2, out, flags);
}

// Round 15
// 7540.709 us; speedup vs baseline: 2.8682x; 1.0617x over previous
//
#include <hip/hip_runtime.h>
#include <hip/hip_bf16.h>

// TrueMarkovChain v15: v14 + two separable changes:
//  (1) act replicas 4 -> 1 (ablation: v11's coalesced stores vs replicas);
//  (2) xc GEMM reads past as bf16 (one-time cvt, ws-guarded fp32 fallback).
// Structure: z1_t = silu(W13·z2_{t-1}+b13+xc_t); A->B 2 hops/step; C off-path
// (Wt3 LDS-pinned); z2 double-buffered; sc0sc1 exchange + coalesced stores;
// PFD16 rings; guarded polls + dead-latch.

typedef __bf16 v8bf __attribute__((ext_vector_type(8)));
typedef float f32x4 __attribute__((ext_vector_type(4)));
typedef unsigned u32x4 __attribute__((ext_vector_type(4)));

#define REP1 (128 * 2048)
#define REP2 (128 * 1024)

__device__ inline f32x4 mfma16(v8bf a, v8bf b, f32x4 c) {
  return __builtin_amdgcn_mfma_f32_16x16x32_bf16(a, b, c, 0, 0, 0);
}
__device__ inline float silu_f(float x) { return x / (1.f + __expf(-x)); }
__device__ inline v8bf as8(f32x4 x) { union { f32x4 f; v8bf b; } u; u.f = x; return u.b; }
__device__ inline v8bf cvt8(float4 a, float4 b) {
  v8bf v;
  v[0] = (__bf16)a.x; v[1] = (__bf16)a.y; v[2] = (__bf16)a.z; v[3] = (__bf16)a.w;
  v[4] = (__bf16)b.x; v[5] = (__bf16)b.y; v[6] = (__bf16)b.z; v[7] = (__bf16)b.w;
  return v;
}
__device__ inline unsigned bfb(float v) {
  __bf16 b = (__bf16)v; unsigned short u; __builtin_memcpy(&u, &b, 2); return (unsigned)u;
}

#define CLOADP(dst, base, boff)                                        \
  asm volatile("global_load_dwordx4 %0, %1, off offset:%2"             \
               : "=v"(dst) : "v"(base), "n"(boff))
#define CLOADC(dst, base)                                              \
  asm volatile("global_load_dwordx4 %0, %1, off sc0 sc1" : "=v"(dst) : "v"(base))

template <int N> __device__ inline void vwait() {
  asm volatile("s_waitcnt vmcnt(%0)" :: "n"(N) : "memory");
  __builtin_amdgcn_sched_barrier(0);
}
__device__ inline void vwait_n(int n) {
  switch (n) {
    case 0: vwait<0>(); break;   case 1: vwait<1>(); break;
    case 2: vwait<2>(); break;   case 3: vwait<3>(); break;
    case 4: vwait<4>(); break;   case 5: vwait<5>(); break;
    case 6: vwait<6>(); break;   case 7: vwait<7>(); break;
    case 8: vwait<8>(); break;   case 9: vwait<9>(); break;
    case 10: vwait<10>(); break; case 11: vwait<11>(); break;
    case 12: vwait<12>(); break; case 13: vwait<13>(); break;
    case 14: vwait<14>(); break; default: vwait<15>(); break;
  }
}

__device__ inline void poll32(const unsigned* f, unsigned tgt, int* dead) {
  if (threadIdx.x < 8 && !*dead) {
    const unsigned* p = f + threadIdx.x * 4;
    int guard = 0;
    while (true) {
      u32x4 v;
      asm volatile("global_load_dwordx4 %0, %1, off sc0 sc1\n\ts_waitcnt vmcnt(0)"
                   : "=v"(v) : "v"(p) : "memory");
      if (v[0] >= tgt && v[1] >= tgt && v[2] >= tgt && v[3] >= tgt) break;
      if (++guard > (1 << 18)) { *dead = 1; break; }
      __builtin_amdgcn_s_sleep(1);
    }
  }
  __syncthreads();
}
__device__ inline void release(unsigned* f, int slot, unsigned v) {
  asm volatile("s_waitcnt vmcnt(0)" ::: "memory");
  __syncthreads();
  if (threadIdx.x == 0)
    asm volatile("global_store_dword %0, %1, off sc0 sc1" :: "v"(f + slot), "v"(v) : "memory");
}

// ---------------- fp32 -> bf16 strided converter -----------------------------
__global__ void cvt_kernel(const float* __restrict__ src, __bf16* __restrict__ dst,
                           int total8, int log2cols, int sstride, int soff) {
  int i = blockIdx.x * 256 + threadIdx.x;
  if (i >= total8) return;
  long long e = (long long)i * 8;
  int r = (int)(e >> log2cols);
  int c = (int)(e & ((1LL << log2cols) - 1));
  const float* s = src + (size_t)r * sstride + soff + c;
  float4 f0 = *(const float4*)(s);
  float4 f1 = *(const float4*)(s + 4);
  *(v8bf*)(dst + e) = cvt8(f0, f1);
}

// ---------------- fp32 (R x C) -> bf16 transposed (C x R) --------------------
__global__ void tpose_kernel(const float* __restrict__ src, __bf16* __restrict__ dst,
                             int R, int C) {
  __shared__ float tile[32][33];
  const int tid = threadIdx.x;
  const int r0 = blockIdx.y * 32, c0 = blockIdx.x * 32;
  const int lr = tid >> 5, lc = tid & 31;
#pragma unroll
  for (int p = 0; p < 4; ++p)
    tile[lr + p * 8][lc] = src[(size_t)(r0 + lr + p * 8) * C + c0 + lc];
  __syncthreads();
#pragma unroll
  for (int p = 0; p < 4; ++p)
    dst[(size_t)(c0 + lr + p * 8) * R + r0 + lc] = (__bf16)tile[lc][lr + p * 8];
}

// ---------------- W13[n][j] = sum_k A[n][k]*B[j][k] (bf16 in/out) ------------
__global__ __launch_bounds__(256, 1) void comp_gemm_kernel(
    const __bf16* __restrict__ A, const __bf16* __restrict__ B,
    __bf16* __restrict__ out) {
  const int tid = threadIdx.x, wid = tid >> 6, lane = tid & 63;
  const int lr = lane & 15, lc = lane >> 4;
  const int m0 = blockIdx.x * 32;
  const int c0 = blockIdx.y * 128 + wid * 32;
  const __bf16* ap0 = A + (size_t)(m0 + lr) * 1024 + lc * 8;
  const __bf16* ap1 = ap0 + (size_t)16 * 1024;
  const __bf16* bp = B + (size_t)(c0 + lr) * 1024 + lc * 8;
  f32x4 acc[2][2] = {};
#pragma unroll 8
  for (int k = 0; k < 1024; k += 32) {
    v8bf a0 = *(const v8bf*)(ap0 + k);
    v8bf a1 = *(const v8bf*)(ap1 + k);
#pragma unroll
    for (int f = 0; f < 2; ++f) {
      v8bf b = *(const v8bf*)(bp + (size_t)f * 16 * 1024 + k);
      acc[0][f] = mfma16(a0, b, acc[0][f]);
      acc[1][f] = mfma16(a1, b, acc[1][f]);
    }
  }
  const int cm = lc << 2, cn = lr;
#pragma unroll
  for (int mf = 0; mf < 2; ++mf)
#pragma unroll
    for (int f = 0; f < 2; ++f)
#pragma unroll
      for (int r = 0; r < 4; ++r)
        out[(size_t)(m0 + mf * 16 + cm + r) * 1024 + c0 + f * 16 + cn] =
            (__bf16)acc[mf][f][r];
}

// ---------------- b13[n] = Wt1s[n]·bt3 ; b1i2[n] = Wt1s[n]·bi2 ---------------
__global__ void bias_comp_kernel(const float* __restrict__ Wt1,
                                 const float* __restrict__ bt3,
                                 const float* __restrict__ bi2,
                                 float* __restrict__ b13, float* __restrict__ b1i2) {
  const int n = blockIdx.x * 4 + (threadIdx.x >> 6);
  const int lane = threadIdx.x & 63;
  const float* row = Wt1 + (size_t)n * 2048;
  float v1 = 0.f, v2 = 0.f;
#pragma unroll
  for (int i = 0; i < 16; ++i) {
    int k = lane + i * 64;
    float w = row[k];
    v1 += w * bt3[k];
    v2 += w * bi2[k];
  }
  for (int o = 32; o; o >>= 1) { v1 += __shfl_down(v1, o); v2 += __shfl_down(v2, o); }
  if (lane == 0) { b13[n] = v1; b1i2[n] = v2; }
}

// ---------------- xc[b][t] = x_t @ Wt1x^T + bt1 (bf16-A fast path) -----------
template <bool BF16A>
__global__ __launch_bounds__(512, 1) void xc_gemm_kernel(
    const void* __restrict__ pastv, const __bf16* __restrict__ w1x,
    const float* __restrict__ bt1, __bf16* __restrict__ xc) {
  const int t = blockIdx.z + 1;
  const int mh = blockIdx.y;
  const int nb = blockIdx.x;
  const int tid = threadIdx.x, wid = tid >> 6, lane = tid & 63;
  const int wm = wid >> 2, wn = wid & 3;
  const int m0 = mh * 64 + wm * 32;
  const int n0 = nb * 512 + wn * 128;
  const int lr = lane & 15, lc = lane >> 4;
  f32x4 acc[2][8] = {};
  const __bf16* bp = w1x + (size_t)(n0 + lr) * 1024 + lc * 8;
  if constexpr (BF16A) {
    const __bf16* a0p = (const __bf16*)pastv +
                        ((size_t)(m0 + lr) * 512 + t) * 1024 + lc * 8;
    const __bf16* a1p = a0p + (size_t)16 * 512 * 1024;
#pragma unroll 4
    for (int k = 0; k < 1024; k += 32) {
      v8bf a0 = *(const v8bf*)(a0p + k);
      v8bf a1 = *(const v8bf*)(a1p + k);
#pragma unroll
      for (int j = 0; j < 8; ++j) {
        v8bf b = *(const v8bf*)(bp + (size_t)j * 16 * 1024 + k);
        acc[0][j] = mfma16(a0, b, acc[0][j]);
        acc[1][j] = mfma16(a1, b, acc[1][j]);
      }
    }
  } else {
    const float* a0p = (const float*)pastv +
                       ((size_t)(m0 + lr) * 512 + t) * 1024 + lc * 8;
    const float* a1p = a0p + (size_t)16 * 512 * 1024;
#pragma unroll 4
    for (int k = 0; k < 1024; k += 32) {
      float4 x00 = *(const float4*)(a0p + k);
      float4 x01 = *(const float4*)(a0p + k + 4);
      float4 x10 = *(const float4*)(a1p + k);
      float4 x11 = *(const float4*)(a1p + k + 4);
      v8bf a0 = cvt8(x00, x01), a1 = cvt8(x10, x11);
#pragma unroll
      for (int j = 0; j < 8; ++j) {
        v8bf b = *(const v8bf*)(bp + (size_t)j * 16 * 1024 + k);
        acc[0][j] = mfma16(a0, b, acc[0][j]);
        acc[1][j] = mfma16(a1, b, acc[1][j]);
      }
    }
  }
  const int cm = lc << 2, cn = lr;
#pragma unroll
  for (int f = 0; f < 2; ++f)
#pragma unroll
    for (int j = 0; j < 8; ++j) {
      int n = n0 + j * 16 + cn;
      float bias = bt1[n];
#pragma unroll
      for (int r = 0; r < 4; ++r) {
        int m = m0 + f * 16 + cm + r;
        xc[((size_t)m * 512 + t) * 2048 + n] = (__bf16)(acc[f][j][r] + bias);
      }
    }
}

// ---- act staging (sc0sc1) -> swizzled LDS -----------------------------------
template <int K>
__device__ inline void stage_issue(f32x4* v, const __bf16* src, int tid) {
  constexpr int KC = K / 8;
#pragma unroll
  for (int i = 0; i < K / 128; ++i) {
    int idx = tid + i * 256;
    int row = idx / KC, kc = idx % KC;
    CLOADC(v[i], src + (size_t)row * K + kc * 8);
  }
}
template <int K>
__device__ inline void stage_commit(char* lds, f32x4* v, int tid) {
  constexpr int KC = K / 8;
#pragma unroll
  for (int i = 0; i < K / 128; ++i) {
    int idx = tid + i * 256;
    int row = idx / KC, kc = idx % KC;
    unsigned byte = ((unsigned)(row * K + kc * 8) * 2) ^ ((unsigned)(row & 7) << 4);
    *(f32x4*)(lds + byte) = v[i];
  }
  __syncthreads();
}

// ---- ring GEMM: swizzled LDS act + plain global weight ring (NF=1) ----------
template <int KIT, int PFD, int KSB>
__device__ inline f32x4 ring_run1(const char* ldsa, int k0, const __bf16* wtb,
                                  f32x4 (&rw)[PFD], int lane) {
  const int lr = lane & 15, lc = lane >> 4;
  f32x4 acc = {0.f, 0.f, 0.f, 0.f};
#pragma unroll
  for (int it = 0; it < KIT; ++it) {
    vwait_n((KIT - 1 - it) < (PFD - 1) ? (KIT - 1 - it) : (PFD - 1));
    v8bf b = as8(rw[it % PFD]);
    if (it + PFD < KIT) CLOADP(rw[it % PFD], wtb, (it + PFD) * 64);
    int k = k0 + it * 32 + lc * 8;
    unsigned byte = ((unsigned)(lr * KSB + k) * 2) ^ ((unsigned)(lr & 7) << 4);
    v8bf a = *(const v8bf*)(ldsa + byte);
    acc = mfma16(a, b, acc);
  }
  return acc;
}
template <int PFD>
__device__ inline void ring_pre(const __bf16* wtb, f32x4 (&rw)[PFD]) {
#pragma unroll
  for (int j = 0; j < PFD; ++j) CLOADP(rw[j], wtb, j * 64);
}

// ---- LDS act + LDS weights ([kb][32][8]) ------------------------------------
__device__ inline f32x4 gemm_aa16(const char* ldsa, int k0, const char* ldsw,
                                  int kb0, int col, int lane) {
  const int lr = lane & 15, lc = lane >> 4;
  f32x4 acc = {0.f, 0.f, 0.f, 0.f};
#pragma unroll
  for (int it = 0; it < 16; ++it) {
    int k = k0 + it * 32 + lc * 8;
    unsigned abyte = ((unsigned)(lr * 1024 + k) * 2) ^ ((unsigned)(lr & 7) << 4);
    v8bf a = *(const v8bf*)(ldsa + abyte);
    v8bf b = *(const v8bf*)(ldsw + (size_t)((kb0 + it * 4 + lc) * 32 + col) * 16);
    acc = mfma16(a, b, acc);
  }
  return acc;
}

// ---------------- persistent recurrence --------------------------------------
__global__ __launch_bounds__(256, 1) void recurrent_kernel(
    const __bf16* __restrict__ wWi1, const __bf16* __restrict__ wWi2,
    const __bf16* __restrict__ wW13, const __bf16* __restrict__ wW1i2,
    const __bf16* __restrict__ wWt2, const __bf16* __restrict__ wWt3,
    const __bf16* __restrict__ x0bf,
    __bf16* __restrict__ z1, __bf16* __restrict__ z2,
    const float* __restrict__ bi1, const float* __restrict__ bi2,
    const float* __restrict__ bt2, const float* __restrict__ bt3,
    const float* __restrict__ b13, const float* __restrict__ b1i2,
    float* __restrict__ out, unsigned* __restrict__ flags) {
  __shared__ alignas(16) char actbuf[65536];   // [16][K<=2048] swizzled acts
  __shared__ alignas(16) char wt3buf[65536];   // Wt3 slice [kb=128][32][8]
  __shared__ alignas(16) char scratch[4096];   // tpose (A) / red+fin (B,C)
  __shared__ int s_dead;
  const int bid = blockIdx.x;
  const int g = bid >> 5, s = bid & 31;
  const int tid = threadIdx.x, wid = tid >> 6, lane = tid & 63;
  const int lr = lane & 15, lc = lane >> 4;
  const int cm = lc << 2, cn = lr;
  const int wn = wid & 1, wk = wid >> 1;
  const int b0 = g * 16;
  if (tid == 0) s_dead = 0;

  unsigned* fA = flags + g * 64;
  unsigned* fB = fA + 32;
  const __bf16* xc = (const __bf16*)out;
  __bf16* tposeb = (__bf16*)scratch;
  float* red = (float*)scratch;
  float* fin = (float*)(scratch + 2048);

  // stage full Wt3 slice (cols s*32..+32, K=1024) -> [kb=128][32][8]
  {
    const __bf16* wg = wWt3 + (size_t)s * 32 * 1024;
    for (int idx = tid; idx < 4096; idx += 256) {
      int kb = idx >> 5, c = idx & 31;
      *(f32x4*)(wt3buf + (size_t)idx * 16) = *(const f32x4*)(wg + (size_t)c * 1024 + kb * 8);
    }
  }

  const int nBC = s * 32 + wn * 16 + cn;
  const int nA = s * 64 + wid * 16 + cn;
  const float bB = bt2[nBC], bCt = bt3[nBC];
  const float bI1 = bi1[nBC], bC0 = bi2[nBC];
  const float bA13 = b13[nA], bA1i2 = b1i2[nA];

  // coalesced store: fin [16][32] fp32 -> bf16 pairs (single copy, rep ablated)
  auto storeZ2 = [&](__bf16* base) {
    int row = tid >> 4, col = (tid * 2) & 31;
    unsigned d = bfb(fin[row * 32 + col]) | (bfb(fin[row * 32 + col + 1]) << 16);
    __bf16* p = base + (size_t)(b0 + row) * 1024 + s * 32 + col;
    asm volatile("global_store_dword %0, %1, off sc0 sc1" :: "v"(p), "v"(d) : "memory");
  };
  auto storeOut = [&](int tt) {
    int row = tid >> 4, col = (tid * 2) & 31;
    float2 o; o.x = fin[row * 32 + col]; o.y = fin[row * 32 + col + 1];
    *(float2*)(out + (size_t)(b0 + row) * 524288 + (size_t)tt * 1024 + s * 32 + col) = o;
  };

  // ---- init-B: h0 = silu(x0 @ Wi1^T + bi1) -> z2 buf0 ----
  {
    f32x4 sv[8];
    stage_issue<1024>(sv, x0bf + (size_t)b0 * 1024, tid);
    f32x4 rw[8];
    const __bf16* wtb = wWi1 + (size_t)(nBC - cn + lr) * 1024 + wk * 512 + lc * 8;
    ring_pre<8>(wtb, rw);
    vwait<0>();
    stage_commit<1024>(actbuf, sv, tid);
    f32x4 acc = ring_run1<16, 8, 1024>(actbuf, wk * 512, wtb, rw, lane);
    if (wk) {
#pragma unroll
      for (int r = 0; r < 4; ++r) red[wn * 256 + (cm + r) * 16 + cn] = acc[r];
    }
    __syncthreads();
    if (!wk) {
#pragma unroll
      for (int r = 0; r < 4; ++r)
        fin[(cm + r) * 32 + wn * 16 + cn] =
            silu_f(acc[r] + red[wn * 256 + (cm + r) * 16 + cn] + bI1);
    }
    __syncthreads();
    storeZ2(z2);  // buf 0
    release(fB, s, 1u);
  }

  for (int t = 1; t < 512; ++t) {
    // ---- A_t: z1 = silu(W(t)·z2_{t-1} + bA + xc[t]) ----
    {
      const __bf16* wtbA = (t == 1 ? wW1i2 : wW13) +
                           (size_t)(s * 64 + wid * 16 + lr) * 1024 + lc * 8;
      const float bAv = (t == 1) ? bA1i2 : bA13;
      unsigned xcu[4];
#pragma unroll
      for (int r = 0; r < 4; ++r) {
        const __bf16* p = xc + ((size_t)(b0 + cm + r) * 512 + t) * 2048 + nA;
        asm volatile("global_load_ushort %0, %1, off sc0 sc1" : "=v"(xcu[r]) : "v"(p));
      }
      f32x4 rw[16];
      ring_pre<16>(wtbA, rw);
      poll32(fB, (unsigned)t, &s_dead);
      f32x4 sv[8];
      stage_issue<1024>(sv, z2 + (size_t)((t - 1) & 1) * REP2 + (size_t)b0 * 1024, tid);
      vwait<0>();
      stage_commit<1024>(actbuf, sv, tid);
      f32x4 acc = ring_run1<32, 16, 1024>(actbuf, 0, wtbA, rw, lane);
#pragma unroll
      for (int r = 0; r < 4; ++r) {
        float xv = __uint_as_float(xcu[r] << 16);
        tposeb[(cm + r) * 64 + wid * 16 + cn] = (__bf16)silu_f(acc[r] + xv + bAv);
      }
      __syncthreads();
      {
        int row = tid >> 4, col = (tid * 4) & 63;
        unsigned long long d = *(const unsigned long long*)(tposeb + row * 64 + col);
        __bf16* p = z1 + (size_t)(b0 + row) * 2048 + s * 64 + col;
        asm volatile("global_store_dwordx2 %0, %1, off sc0 sc1" :: "v"(p), "v"(d) : "memory");
      }
      release(fA, s, (unsigned)t);
    }
    // ---- C_{t-1} (off-path): out[:,t-1,:] from staged z2_{t-1} ----
    {
      f32x4 acc;
      if (t == 1) {
        const __bf16* wtbC = wWi2 + (size_t)(nBC - cn + lr) * 1024 + wk * 512 + lc * 8;
        f32x4 rw[8];
        ring_pre<8>(wtbC, rw);
        acc = ring_run1<16, 8, 1024>(actbuf, wk * 512, wtbC, rw, lane);
      } else {
        acc = gemm_aa16(actbuf, wk * 512, wt3buf, wk * 64, wn * 16 + lr, lane);
      }
      const float bCv = (t == 1) ? bC0 : bCt;
      if (wk) {
#pragma unroll
        for (int r = 0; r < 4; ++r) red[wn * 256 + (cm + r) * 16 + cn] = acc[r];
      }
      __syncthreads();
      if (!wk) {
#pragma unroll
        for (int r = 0; r < 4; ++r)
          fin[(cm + r) * 32 + wn * 16 + cn] =
              acc[r] + red[wn * 256 + (cm + r) * 16 + cn] + bCv;
      }
      __syncthreads();
      storeOut(t - 1);
    }
    // ---- B_t: z2[t&1] = silu(z1 @ Wt2^T + bt2) ----
    {
      const __bf16* wtbB = wWt2 + (size_t)(nBC - cn + lr) * 2048 + wk * 1024 + lc * 8;
      f32x4 rw[16];
      ring_pre<16>(wtbB, rw);
      poll32(fA, (unsigned)t, &s_dead);
      f32x4 sv[16];
      stage_issue<2048>(sv, z1 + (size_t)b0 * 2048, tid);
      vwait<0>();
      stage_commit<2048>(actbuf, sv, tid);
      f32x4 acc = ring_run1<32, 16, 2048>(actbuf, wk * 1024, wtbB, rw, lane);
      if (wk) {
#pragma unroll
        for (int r = 0; r < 4; ++r) red[wn * 256 + (cm + r) * 16 + cn] = acc[r];
      }
      __syncthreads();
      if (!wk) {
#pragma unroll
        for (int r = 0; r < 4; ++r)
          fin[(cm + r) * 32 + wn * 16 + cn] =
              silu_f(acc[r] + red[wn * 256 + (cm + r) * 16 + cn] + bB);
      }
      __syncthreads();
      storeZ2(z2 + (size_t)(t & 1) * REP2);
      release(fB, s, (unsigned)(t + 1));
    }
  }
  // ---- epilogue: C_511 -> out[:,511,:] ----
  {
    poll32(fB, 512u, &s_dead);
    f32x4 sv[8];
    stage_issue<1024>(sv, z2 + (size_t)1 * REP2 + (size_t)b0 * 1024, tid);
    vwait<0>();
    stage_commit<1024>(actbuf, sv, tid);
    f32x4 acc = gemm_aa16(actbuf, wk * 512, wt3buf, wk * 64, wn * 16 + lr, lane);
    if (wk) {
#pragma unroll
      for (int r = 0; r < 4; ++r) red[wn * 256 + (cm + r) * 16 + cn] = acc[r];
    }
    __syncthreads();
    if (!wk) {
#pragma unroll
      for (int r = 0; r < 4; ++r)
        fin[(cm + r) * 32 + wn * 16 + cn] =
            acc[r] + red[wn * 256 + (cm + r) * 16 + cn] + bCt;
    }
    __syncthreads();
    storeOut(511);
  }
}

// ---------------- host launcher ----------------------------------------------
extern "C" void kernel_launch(void* const* d_in, const int* in_sizes, int n_in,
                              void* d_out, int out_size, void* d_ws, size_t ws_size,
                              hipStream_t stream) {
  (void)in_sizes; (void)n_in; (void)out_size;
  const float* past = (const float*)d_in[0];
  const float* Wi1 = (const float*)d_in[1];
  const float* bi1 = (const float*)d_in[2];
  const float* Wi2 = (const float*)d_in[3];
  const float* bi2 = (const float*)d_in[4];
  const float* Wt1 = (const float*)d_in[5];
  const float* bt1 = (const float*)d_in[6];
  const float* Wt2 = (const float*)d_in[7];
  const float* bt2 = (const float*)d_in[8];
  const float* Wt3 = (const float*)d_in[9];
  const float* bt3 = (const float*)d_in[10];
  float* out = (float*)d_out;

  char* ws = (char*)d_ws;
  size_t off = 0;
  unsigned* flags = (unsigned*)(ws + off); off += 4096;
  __bf16* wWi1 = (__bf16*)(ws + off);  off += (size_t)1024 * 1024 * 2;
  __bf16* wWi2 = (__bf16*)(ws + off);  off += (size_t)1024 * 1024 * 2;
  __bf16* wWt1s = (__bf16*)(ws + off); off += (size_t)2048 * 1024 * 2;
  __bf16* wWt1x = (__bf16*)(ws + off); off += (size_t)2048 * 1024 * 2;
  __bf16* wWt2 = (__bf16*)(ws + off);  off += (size_t)1024 * 2048 * 2;
  __bf16* wWt3 = (__bf16*)(ws + off);  off += (size_t)1024 * 1024 * 2;
  __bf16* wWt3T = (__bf16*)(ws + off); off += (size_t)1024 * 1024 * 2;
  __bf16* wWi2T = (__bf16*)(ws + off); off += (size_t)1024 * 1024 * 2;
  __bf16* wW13 = (__bf16*)(ws + off);  off += (size_t)2048 * 1024 * 2;
  __bf16* wW1i2 = (__bf16*)(ws + off); off += (size_t)2048 * 1024 * 2;
  float* b13 = (float*)(ws + off);     off += 2048 * 4;
  float* b1i2 = (float*)(ws + off);    off += 2048 * 4;
  __bf16* x0bf = (__bf16*)(ws + off);  off += (size_t)128 * 1024 * 2;
  __bf16* z1 = (__bf16*)(ws + off);    off += (size_t)REP1 * 2;
  __bf16* z2 = (__bf16*)(ws + off);    off += (size_t)2 * REP2 * 2;
  __bf16* pbf = (__bf16*)(ws + off);
  const size_t need_pbf = off + (size_t)128 * 512 * 1024 * 2;
  const bool use_pbf = ws_size >= need_pbf;

  hipMemsetAsync(flags, 0, 4096, stream);

  auto cvt = [&](const float* s, __bf16* d, size_t rows, int cols, int log2c,
                 int sstride, int soff) {
    int total8 = (int)(rows * (size_t)cols / 8);
    cvt_kernel<<<dim3((total8 + 255) / 256), dim3(256), 0, stream>>>(
        s, d, total8, log2c, sstride, soff);
  };
  cvt(Wi1, wWi1, 1024, 1024, 10, 1024, 0);
  cvt(Wi2, wWi2, 1024, 1024, 10, 1024, 0);
  cvt(Wt1, wWt1s, 2048, 1024, 10, 2048, 0);
  cvt(Wt1, wWt1x, 2048, 1024, 10, 2048, 1024);
  cvt(Wt2, wWt2, 1024, 2048, 11, 2048, 0);
  cvt(Wt3, wWt3, 1024, 1024, 10, 1024, 0);
  cvt(past, x0bf, 128, 1024, 10, 512 * 1024, 0);

  tpose_kernel<<<dim3(32, 32), dim3(256), 0, stream>>>(Wt3, wWt3T, 1024, 1024);
  tpose_kernel<<<dim3(32, 32), dim3(256), 0, stream>>>(Wi2, wWi2T, 1024, 1024);
  comp_gemm_kernel<<<dim3(64, 8), dim3(256), 0, stream>>>(wWt1s, wWt3T, wW13);
  comp_gemm_kernel<<<dim3(64, 8), dim3(256), 0, stream>>>(wWt1s, wWi2T, wW1i2);
  bias_comp_kernel<<<dim3(512), dim3(256), 0, stream>>>(Wt1, bt3, bi2, b13, b1i2);

  if (use_pbf) {
    cvt(past, pbf, (size_t)128 * 512, 1024, 10, 1024, 0);
    xc_gemm_kernel<true><<<dim3(4, 2, 511), dim3(512), 0, stream>>>(
        pbf, wWt1x, bt1, (__bf16*)d_out);
  } else {
    xc_gemm_kernel<false><<<dim3(4, 2, 511), dim3(512), 0, stream>>>(
        past, wWt1x, bt1, (__bf16*)d_out);
  }

  recurrent_kernel<<<dim3(256), dim3(256), 0, stream>>>(
      wWi1, wWi2, wW13, wW1i2, wWt2, wWt3, x0bf, z1, z2,
      bi1, bi2, bt2, bt3, b13, b1i2, out, flags);
}